// Round 12
// baseline (157.886 us; speedup 1.0000x reference)
//
#include <hip/hip_runtime.h>
#include <stdint.h>
#include <math.h>

// SFIS: F=16, D=64, N=100000, B=2048, ORDER=3, BETA=1e-4, H=64
#define NB    2048
#define NE    680     // 120 pairs + 560 triples
#define L1N   120
#define L2N   560
#define KEEP2 455     // triples with A<=12 feed the regularizer
#define ROWP  68      // padded LDS row stride (floats) for V0s/Z0s
#define NT    43      // 16-row MFMA tiles covering 688 >= 680 rows
#define NSL   688     // NT*16
#define WLOS  72      // W1loT LDS row stride in ushorts (pad: bank-balanced b128)

#define THREEFRY_PARTITIONABLE 1

typedef __attribute__((ext_vector_type(8))) short bf16x8;
typedef __attribute__((ext_vector_type(4))) float f32x4;
typedef __attribute__((ext_vector_type(2))) float f32x2;
typedef __attribute__((ext_vector_type(4))) uint32_t u32x4;

union ABfrag { bf16x8 v; uint32_t u[4]; };

__device__ __forceinline__ uint32_t rotl32(uint32_t v, uint32_t d) {
  return (v << d) | (v >> (32u - d));
}

// f32 -> bf16 bits, round-nearest-even (finite inputs only)
__device__ __forceinline__ uint32_t bf_rne(float f) {
  uint32_t u = __float_as_uint(f);
  return (u + 0x7fffu + ((u >> 16) & 1u)) >> 16;
}

// JAX threefry2x32 (jax/_src/prng.py), 20 rounds.
__device__ __forceinline__ void tf2x32(uint32_t k0, uint32_t k1,
                                       uint32_t c0, uint32_t c1,
                                       uint32_t &o0, uint32_t &o1) {
  uint32_t ks2 = k0 ^ k1 ^ 0x1BD11BDAu;
  uint32_t x0 = c0 + k0;
  uint32_t x1 = c1 + k1;
#define TF_R(r) { x0 += x1; x1 = rotl32(x1, r); x1 ^= x0; }
  TF_R(13) TF_R(15) TF_R(26) TF_R(6)
  x0 += k1;  x1 += ks2 + 1u;
  TF_R(17) TF_R(29) TF_R(16) TF_R(24)
  x0 += ks2; x1 += k0 + 2u;
  TF_R(13) TF_R(15) TF_R(26) TF_R(6)
  x0 += k0;  x1 += k1 + 3u;
  TF_R(17) TF_R(29) TF_R(16) TF_R(24)
  x0 += k1;  x1 += ks2 + 4u;
  TF_R(13) TF_R(15) TF_R(26) TF_R(6)
  x0 += ks2; x1 += k0 + 5u;
#undef TF_R
  o0 = x0; o1 = x1;
}

// One-shot per-launch precompute of block-invariant data (descs + W1 splits
// in fragment layout [n][k]). Grid = 17 blocks: 0..15 split W1, 16 builds descs.
__global__ __launch_bounds__(256) void sfis_setup(
    const float* __restrict__ W1,
    unsigned short* __restrict__ ws_descs,   // [688]
    unsigned short* __restrict__ ws_w1hi,    // [64][64], n-major
    unsigned short* __restrict__ ws_w1lo) {  // [64][64], n-major
  const int bid = blockIdx.x, tid = threadIdx.x;
  if (bid == 16) {
    for (int e = tid; e < NSL; e += 256) {
      int fi, fj, fl, lvl;
      if (e < L1N) {                      // pair: V0f[a+1] * V0f[k]
        int a = 0;
        while ((a + 1) * (a + 2) / 2 <= e) ++a;
        int k = e - a * (a + 1) / 2;
        fi = a + 1; fj = k; fl = 16; lvl = 0;   // fl=16 -> ones row
      } else if (e < NE) {                // triple: V0f[A+2] * (V0f[a1+1]*V0f[k1])
        int e2 = e - L1N;
        int A = 0;
        while ((A + 1) * (A + 2) * (A + 3) / 6 <= e2) ++A;
        int k = e2 - A * (A + 1) * (A + 2) / 6;
        int a1 = 0;
        while ((a1 + 1) * (a1 + 2) / 2 <= k) ++a1;
        int k1 = k - a1 * (a1 + 1) / 2;
        fi = A + 2; fj = a1 + 1; fl = k1; lvl = 1;
      } else {                            // dummy rows 680..687 -> ones product
        fi = 16; fj = 16; fl = 16; lvl = 0;
      }
      ws_descs[e] = (unsigned short)((uint32_t)fi | ((uint32_t)fj << 5) |
                                     ((uint32_t)fl << 10) | ((uint32_t)lvl << 15));
    }
  } else {
    int i = bid * 256 + tid;            // i = k*64 + n over W1[64][64]
    int k = i >> 6, n = i & 63;
    float w = W1[i];
    uint32_t hb = bf_rne(w);
    float hf = __uint_as_float(hb << 16);
    uint32_t lb = bf_rne(w - hf);
    ws_w1hi[n * 64 + k] = (unsigned short)hb;
    ws_w1lo[n * 64 + k] = (unsigned short)lb;
  }
}

// R7 champion shape: 256 threads, ~25.5 KB LDS (6 blocks/CU), Bh in regs,
// Bl streamed from LDS. VGPR ~80. Do NOT grow LDS or merge phases (R6/R8/R9).
// R12: hot f32 arithmetic in f32x2 to engage v_pk_{mul,add,fma,max}_f32.
__global__ __launch_bounds__(256, 8) void sfis_main(
    const int*   __restrict__ x,
    const float* __restrict__ M,
    const float* __restrict__ w0,
    const float* __restrict__ w_table,
    const float* __restrict__ V_table,
    const float* __restrict__ Z_table,
    const float* __restrict__ b1,
    const float* __restrict__ W2,
    const float* __restrict__ b2,
    const unsigned short* __restrict__ ws_descs,
    const unsigned short* __restrict__ ws_w1hi,
    const unsigned short* __restrict__ ws_w1lo,
    float* __restrict__ out,
    float* __restrict__ reg_partial) {
  __shared__ __align__(16) float V0s[17 * ROWP];  // row 16 = ones
  __shared__ __align__(16) float Z0s[17 * ROWP];
  __shared__ __align__(16) unsigned short W1loT[64 * WLOS];
  __shared__ __align__(4) unsigned short descs16[NSL];
  __shared__ float wts[NSL];
  __shared__ float t2s[NSL];
  __shared__ float W2s[64];
  __shared__ int xs[16];
  __shared__ float red8[8];
  __shared__ float wsum_s, w2sum_s;

  const int b   = blockIdx.x;
  const int tid = threadIdx.x;

  // ---- phase A: indices, ones rows, copy precomputed descs + W1lo table ----
  if (tid < 16) xs[tid] = x[b * 16 + tid];
  if (tid < 64) {
    W2s[tid] = W2[tid];
    V0s[16 * ROWP + tid] = 1.f;
    Z0s[16 * ROWP + tid] = 1.f;
  }
  for (int i = tid; i < NSL / 2; i += 256)    // 344 dwords
    ((uint32_t*)descs16)[i] = ((const uint32_t*)ws_descs)[i];
  for (int i = tid; i < 512; i += 256) {      // 64 rows x 8 chunks of 16B
    int n = i >> 3, ch = i & 7;
    *(u32x4*)((char*)W1loT + n * (WLOS * 2) + ch * 16) =
        *(const u32x4*)((const char*)ws_w1lo + n * 128 + ch * 16);
  }
  __syncthreads();

  // ---- phase C: V0f = M @ V, Z0f = M @ Z (paired V/Z pk_fma) ----
  if (tid == 0) {
    float s = 0.f, s2 = 0.f;
    for (int f = 0; f < 16; ++f) {
      float wv = w_table[xs[f]];
      s += wv; s2 += wv * wv;
    }
    wsum_s = s; w2sum_s = s2;
  }
  for (int idx = tid; idx < 1024; idx += 256) {
    int f = idx >> 6, d = idx & 63;
    f32x2 acc2 = {0.f, 0.f};
    for (int g = 0; g < 16; ++g) {
      float m = M[f * 16 + g];          // wave-uniform -> s_load
      long off = (long)xs[g] * 64 + d;  // coalesced over d
      f32x2 vz = {V_table[off], Z_table[off]};
      acc2 = __builtin_elementwise_fma((f32x2){m, m}, vz, acc2);
    }
    V0s[f * ROWP + d] = acc2.x;
    Z0s[f * ROWP + d] = acc2.y;
  }
  __syncthreads();

  // ---- phase D1: Wt / vsq on VALU (pk pairs); Wt -> LDS ----
  float v2acc = 0.f;
  for (int e0 = 0; e0 < 768; e0 += 256) {
    const int e = e0 + tid;
    const bool valid = (e < NE);
    uint32_t dsc = valid ? (uint32_t)descs16[e] : 0x4210u;
    const int oI = (int)(dsc & 31) * ROWP;
    const int oJ = (int)((dsc >> 5) & 31) * ROWP;
    const int oL = (int)((dsc >> 10) & 31) * ROWP;
    const int lvl = (dsc >> 15) & 1;

    f32x2 wt2 = {0.f, 0.f}, vs2 = {0.f, 0.f};
    for (int dq = 0; dq < 16; ++dq) {
      float4 a = *(const float4*)&V0s[oJ + (dq << 2)];
      float4 c = *(const float4*)&V0s[oL + (dq << 2)];
      float4 v = *(const float4*)&V0s[oI + (dq << 2)];
      f32x2 p01 = (f32x2){v.x, v.y} * ((f32x2){a.x, a.y} * (f32x2){c.x, c.y});
      f32x2 p23 = (f32x2){v.z, v.w} * ((f32x2){a.z, a.w} * (f32x2){c.z, c.w});
      wt2 += p01;
      wt2 += p23;
      vs2 = __builtin_elementwise_fma(p01, p01, vs2);
      vs2 = __builtin_elementwise_fma(p23, p23, vs2);
    }
    if (valid) wts[e] = wt2.x + wt2.y;
    if (valid && lvl && (uint32_t)(e - L1N) < (uint32_t)KEEP2)
      v2acc += vs2.x + vs2.y;
  }

  // ---- phase D2: MLP hidden layer, bf16x3 MFMA GEMM (h = Z_sel@W1 + b1) ----
  // acc += Ah*Bh + Al*Bh + Ah*Bl. Ah = trunc(z), Al = trunc(z - Ah).
  // z-products + Al-subtract in f32x2 (pk); gate values bit-identical to R11.
  {
    const int lane = tid & 63;
    const int wave = tid >> 6;
    const int col  = lane & 15;   // A-row / D-col / B-col within 16-tile
    const int kg   = lane >> 4;   // k-group: this lane's 8 contiguous k

    bf16x8 Bh[2][4];
#pragma unroll
    for (int ks = 0; ks < 2; ++ks)
#pragma unroll
      for (int c = 0; c < 4; ++c)
        Bh[ks][c] = *(const bf16x8*)&ws_w1hi[(c * 16 + col) * 64 + ks * 32 + kg * 8];
    float bv0 = b1[col], bv1 = b1[16 + col], bv2 = b1[32 + col], bv3 = b1[48 + col];

    for (int t = wave; t < NT; t += 4) {
      const int er = 16 * t + col;
      const uint32_t dsc = (uint32_t)descs16[er];
      const int oI = (int)(dsc & 31) * ROWP;
      const int oJ = (int)((dsc >> 5) & 31) * ROWP;
      const int oL = (int)((dsc >> 10) & 31) * ROWP;

      f32x4 acc[4];
      acc[0] = (f32x4){bv0, bv0, bv0, bv0};
      acc[1] = (f32x4){bv1, bv1, bv1, bv1};
      acc[2] = (f32x4){bv2, bv2, bv2, bv2};
      acc[3] = (f32x4){bv3, bv3, bv3, bv3};

#pragma unroll
      for (int ks = 0; ks < 2; ++ks) {
        const int kc = ks * 32 + kg * 8;
        float4 a0 = *(const float4*)&Z0s[oJ + kc];
        float4 c0 = *(const float4*)&Z0s[oL + kc];
        float4 z0 = *(const float4*)&Z0s[oI + kc];
        float4 a1 = *(const float4*)&Z0s[oJ + kc + 4];
        float4 c1 = *(const float4*)&Z0s[oL + kc + 4];
        float4 z1 = *(const float4*)&Z0s[oI + kc + 4];

        f32x2 zp[4];
        zp[0] = (f32x2){z0.x, z0.y} * ((f32x2){a0.x, a0.y} * (f32x2){c0.x, c0.y});
        zp[1] = (f32x2){z0.z, z0.w} * ((f32x2){a0.z, a0.w} * (f32x2){c0.z, c0.w});
        zp[2] = (f32x2){z1.x, z1.y} * ((f32x2){a1.x, a1.y} * (f32x2){c1.x, c1.y});
        zp[3] = (f32x2){z1.z, z1.w} * ((f32x2){a1.z, a1.w} * (f32x2){c1.z, c1.w});

        ABfrag Ah, Al;
#pragma unroll
        for (int p = 0; p < 4; ++p) {
          uint32_t uz0 = __float_as_uint(zp[p].x);
          uint32_t uz1 = __float_as_uint(zp[p].y);
          Ah.u[p] = __builtin_amdgcn_perm(uz1, uz0, 0x07060302u);
          f32x2 hf = { __uint_as_float(uz0 & 0xffff0000u),
                       __uint_as_float(uz1 & 0xffff0000u) };
          f32x2 dl = zp[p] - hf;          // v_pk_add_f32 (neg)
          Al.u[p] = __builtin_amdgcn_perm(__float_as_uint(dl.y),
                                          __float_as_uint(dl.x), 0x07060302u);
        }
#pragma unroll
        for (int c = 0; c < 4; ++c)
          acc[c] = __builtin_amdgcn_mfma_f32_16x16x32_bf16(Ah.v, Bh[ks][c], acc[c], 0, 0, 0);
#pragma unroll
        for (int c = 0; c < 4; ++c)
          acc[c] = __builtin_amdgcn_mfma_f32_16x16x32_bf16(Al.v, Bh[ks][c], acc[c], 0, 0, 0);
#pragma unroll
        for (int c = 0; c < 4; ++c) {
          bf16x8 Blf = *(const bf16x8*)&W1loT[(c * 16 + col) * WLOS + ks * 32 + kg * 8];
          acc[c] = __builtin_amdgcn_mfma_f32_16x16x32_bf16(Ah.v, Blf, acc[c], 0, 0, 0);
        }
      }

      // second layer: t2 = relu(h) @ W2 (pk max/fma), reduce across 16 cols
      const f32x2 zero2 = {0.f, 0.f};
      f32x2 q01 = {0.f, 0.f}, q23 = {0.f, 0.f};
#pragma unroll
      for (int c = 0; c < 4; ++c) {
        float w2v = W2s[c * 16 + col];
        f32x2 w22 = {w2v, w2v};
        f32x2 h01 = {acc[c][0], acc[c][1]};
        f32x2 h23 = {acc[c][2], acc[c][3]};
        q01 = __builtin_elementwise_fma(__builtin_elementwise_max(h01, zero2), w22, q01);
        q23 = __builtin_elementwise_fma(__builtin_elementwise_max(h23, zero2), w22, q23);
      }
      float p0 = q01.x, p1 = q01.y, p2 = q23.x, p3 = q23.y;
#pragma unroll
      for (int m = 1; m < 16; m <<= 1) {
        p0 += __shfl_xor(p0, m, 16);
        p1 += __shfl_xor(p1, m, 16);
        p2 += __shfl_xor(p2, m, 16);
        p3 += __shfl_xor(p3, m, 16);
      }
      const int rb = 16 * t + kg * 4;   // D rows this lane-group owns
      if      (col == 0) t2s[rb + 0] = p0;
      else if (col == 1) t2s[rb + 1] = p1;
      else if (col == 2) t2s[rb + 2] = p2;
      else if (col == 3) t2s[rb + 3] = p3;
    }
  }
  __syncthreads();

  // ---- phase D3: eps (threefry), sigmoid (fast f32 + guarded f64), gate ----
  uint32_t fkA0, fkA1, fkB0, fkB1;   // fold_in(key(42), 0) and (.,1)
  tf2x32(0u, 42u, 0u, 0u, fkA0, fkA1);
  tf2x32(0u, 42u, 0u, 1u, fkB0, fkB1);
  const float b2v = b2[0];

  float yacc = 0.f;
  for (int e0 = 0; e0 < 768; e0 += 256) {
    const int e = e0 + tid;
    const bool valid = (e < NE);
    uint32_t dsc = valid ? (uint32_t)descs16[e] : 0x4210u;
    const int lvl = (dsc >> 15) & 1;

    float t2 = (valid ? t2s[e] : 0.f) + b2v;

    uint32_t Lsz  = lvl ? (uint32_t)L2N : (uint32_t)L1N;
    uint32_t lidx = lvl ? (uint32_t)(e - L1N) : (uint32_t)e;
    uint32_t kk0  = lvl ? fkB0 : fkA0;
    uint32_t kk1  = lvl ? fkB1 : fkA1;
    uint32_t gi   = (uint32_t)b * Lsz + lidx;
    uint32_t o0, o1, bits;
#if THREEFRY_PARTITIONABLE
    tf2x32(kk0, kk1, 0u, gi, o0, o1);
    bits = o0 ^ o1;
#else
    {
      uint32_t half = Lsz * (NB / 2);
      if (gi < half) { tf2x32(kk0, kk1, gi, gi + half, o0, o1); bits = o0; }
      else           { tf2x32(kk0, kk1, gi - half, gi, o0, o1); bits = o1; }
    }
#endif
    float eps = __uint_as_float((bits >> 9) | 0x3f800000u) - 1.0f;

    // fast f32 sigmoid; exact f64 only in the ambiguity window. Decisions
    // identical to the pure-f64 path (validated R8-R11, absmax 0.0).
    float pf = 1.0f / (1.0f + __expf(-t2));
    bool gate;
    if (fabsf(pf - eps) > 1e-4f) {
      gate = (pf >= eps);
    } else {
      double ex = exp(-(double)t2);
      float pro = (float)(1.0 / (1.0 + ex));
      gate = (pro >= eps);
    }
    if (valid && gate) yacc += wts[e];
  }

  // ---- phase E: wave-shuffle reduction, one barrier ----
  {
#pragma unroll
    for (int m = 32; m > 0; m >>= 1) {
      yacc  += __shfl_down(yacc, m, 64);
      v2acc += __shfl_down(v2acc, m, 64);
    }
    if ((tid & 63) == 0) {
      red8[tid >> 6]       = yacc;
      red8[4 + (tid >> 6)] = v2acc;
    }
    __syncthreads();
    if (tid == 0) {
      out[b] = w0[0] + wsum_s + ((red8[0] + red8[1]) + (red8[2] + red8[3]));
      reg_partial[b] = w2sum_s + ((red8[4] + red8[5]) + (red8[6] + red8[7]));
    }
  }
}

__global__ __launch_bounds__(256) void sfis_reduce(
    const float* __restrict__ reg_partial, float* __restrict__ out) {
  __shared__ float red[256];
  int tid = threadIdx.x;
  float s = 0.f;
  for (int i = tid; i < NB; i += 256) s += reg_partial[i];
  red[tid] = s;
  __syncthreads();
  for (int st = 128; st > 0; st >>= 1) {
    if (tid < st) red[tid] += red[tid + st];
    __syncthreads();
  }
  if (tid == 0) out[NB] = 1.0e-4f * red[0];  // BETA
}

extern "C" void kernel_launch(void* const* d_in, const int* in_sizes, int n_in,
                              void* d_out, int out_size, void* d_ws, size_t ws_size,
                              hipStream_t stream) {
  (void)in_sizes; (void)n_in; (void)out_size; (void)ws_size;
  const int*   x       = (const int*)  d_in[0];
  const float* M       = (const float*)d_in[1];
  const float* w0      = (const float*)d_in[2];
  const float* w_table = (const float*)d_in[3];
  const float* V_table = (const float*)d_in[4];
  const float* Z_table = (const float*)d_in[5];
  const float* W1      = (const float*)d_in[6];
  const float* b1      = (const float*)d_in[7];
  const float* W2      = (const float*)d_in[8];
  const float* b2      = (const float*)d_in[9];
  float* out  = (float*)d_out;

  // d_ws layout: [0,1376) descs | [2048,10240) W1hi | [10240,18432) W1lo |
  //              [20480, +8KB) reg partials
  unsigned short* ws_descs = (unsigned short*)d_ws;
  unsigned short* ws_w1hi  = (unsigned short*)((char*)d_ws + 2048);
  unsigned short* ws_w1lo  = (unsigned short*)((char*)d_ws + 10240);
  float*          regp     = (float*)((char*)d_ws + 20480);

  hipLaunchKernelGGL(sfis_setup, dim3(17), dim3(256), 0, stream,
                     W1, ws_descs, ws_w1hi, ws_w1lo);
  hipLaunchKernelGGL(sfis_main, dim3(NB), dim3(256), 0, stream,
                     x, M, w0, w_table, V_table, Z_table, b1, W2, b2,
                     ws_descs, ws_w1hi, ws_w1lo, out, regp);
  hipLaunchKernelGGL(sfis_reduce, dim3(1), dim3(256), 0, stream, regp, out);
}

// Round 13
// 89.349 us; speedup vs baseline: 1.7671x; 1.7671x over previous
//
#include <hip/hip_runtime.h>
#include <stdint.h>
#include <math.h>

// SFIS: F=16, D=64, N=100000, B=2048, ORDER=3, BETA=1e-4, H=64
#define NB    2048
#define NE    680     // 120 pairs + 560 triples
#define L1N   120
#define L2N   560
#define KEEP2 455     // triples with A<=12 feed the regularizer
#define ROWP  68      // padded LDS row stride (floats) for V0s/Z0s
#define NT    43      // 16-row MFMA tiles covering 688 >= 680 rows
#define NSL   688     // NT*16
#define WLOS  72      // W1loT LDS row stride in ushorts (pad: bank-balanced b128)

#define THREEFRY_PARTITIONABLE 1

typedef __attribute__((ext_vector_type(8))) short bf16x8;
typedef __attribute__((ext_vector_type(4))) float f32x4;
typedef __attribute__((ext_vector_type(4))) uint32_t u32x4;

union ABfrag { bf16x8 v; uint32_t u[4]; };

__device__ __forceinline__ uint32_t rotl32(uint32_t v, uint32_t d) {
  return (v << d) | (v >> (32u - d));
}

// f32 -> bf16 bits, round-nearest-even (finite inputs only)
__device__ __forceinline__ uint32_t bf_rne(float f) {
  uint32_t u = __float_as_uint(f);
  return (u + 0x7fffu + ((u >> 16) & 1u)) >> 16;
}

// JAX threefry2x32 (jax/_src/prng.py), 20 rounds.
__device__ __forceinline__ void tf2x32(uint32_t k0, uint32_t k1,
                                       uint32_t c0, uint32_t c1,
                                       uint32_t &o0, uint32_t &o1) {
  uint32_t ks2 = k0 ^ k1 ^ 0x1BD11BDAu;
  uint32_t x0 = c0 + k0;
  uint32_t x1 = c1 + k1;
#define TF_R(r) { x0 += x1; x1 = rotl32(x1, r); x1 ^= x0; }
  TF_R(13) TF_R(15) TF_R(26) TF_R(6)
  x0 += k1;  x1 += ks2 + 1u;
  TF_R(17) TF_R(29) TF_R(16) TF_R(24)
  x0 += ks2; x1 += k0 + 2u;
  TF_R(13) TF_R(15) TF_R(26) TF_R(6)
  x0 += k0;  x1 += k1 + 3u;
  TF_R(17) TF_R(29) TF_R(16) TF_R(24)
  x0 += k1;  x1 += ks2 + 4u;
  TF_R(13) TF_R(15) TF_R(26) TF_R(6)
  x0 += ks2; x1 += k0 + 5u;
#undef TF_R
  o0 = x0; o1 = x1;
}

// One-shot per-launch precompute. Blocks 0..15: W1 hi/lo split in fragment
// layout [n][k]. Block 16: interaction descriptors. Blocks 17+: per-(b,e)
// gate thresholds (thr = logit(eps) in f64, + eps for the guard window) --
// eps is input-independent (threefry of b,e only), so it is hoisted here.
__global__ __launch_bounds__(256) void sfis_setup(
    const float* __restrict__ W1,
    unsigned short* __restrict__ ws_descs,   // [688]
    unsigned short* __restrict__ ws_w1hi,    // [64][64], n-major
    unsigned short* __restrict__ ws_w1lo,    // [64][64], n-major
    float2* __restrict__ ws_epsthr) {        // [NB][NSL] {thr, eps}
  const int bid = blockIdx.x, tid = threadIdx.x;
  if (bid == 16) {
    for (int e = tid; e < NSL; e += 256) {
      int fi, fj, fl, lvl;
      if (e < L1N) {                      // pair: V0f[a+1] * V0f[k]
        int a = 0;
        while ((a + 1) * (a + 2) / 2 <= e) ++a;
        int k = e - a * (a + 1) / 2;
        fi = a + 1; fj = k; fl = 16; lvl = 0;   // fl=16 -> ones row
      } else if (e < NE) {                // triple: V0f[A+2] * (V0f[a1+1]*V0f[k1])
        int e2 = e - L1N;
        int A = 0;
        while ((A + 1) * (A + 2) * (A + 3) / 6 <= e2) ++A;
        int k = e2 - A * (A + 1) * (A + 2) / 6;
        int a1 = 0;
        while ((a1 + 1) * (a1 + 2) / 2 <= k) ++a1;
        int k1 = k - a1 * (a1 + 1) / 2;
        fi = A + 2; fj = a1 + 1; fl = k1; lvl = 1;
      } else {                            // dummy rows 680..687 -> ones product
        fi = 16; fj = 16; fl = 16; lvl = 0;
      }
      ws_descs[e] = (unsigned short)((uint32_t)fi | ((uint32_t)fj << 5) |
                                     ((uint32_t)fl << 10) | ((uint32_t)lvl << 15));
    }
  } else if (bid < 16) {
    int i = bid * 256 + tid;            // i = k*64 + n over W1[64][64]
    int k = i >> 6, n = i & 63;
    float w = W1[i];
    uint32_t hb = bf_rne(w);
    float hf = __uint_as_float(hb << 16);
    uint32_t lb = bf_rne(w - hf);
    ws_w1hi[n * 64 + k] = (unsigned short)hb;
    ws_w1lo[n * 64 + k] = (unsigned short)lb;
  } else {
    int flat = (bid - 17) * 256 + tid;  // over NB*NSL
    if (flat < NB * NSL) {
      int b = flat / NSL, e = flat - b * NSL;
      int lvl = (e >= L1N) ? 1 : 0;
      uint32_t Lsz  = lvl ? (uint32_t)L2N : (uint32_t)L1N;
      uint32_t lidx = lvl ? (uint32_t)(e - L1N) : (uint32_t)e;
      uint32_t fk0, fk1, o0, o1;
      tf2x32(0u, 42u, 0u, (uint32_t)lvl, fk0, fk1);  // fold_in(key(42), lvl)
      uint32_t gi = (uint32_t)b * Lsz + lidx;
      uint32_t bits;
#if THREEFRY_PARTITIONABLE
      tf2x32(fk0, fk1, 0u, gi, o0, o1);
      bits = o0 ^ o1;
#else
      {
        uint32_t half = Lsz * (NB / 2);
        if (gi < half) { tf2x32(fk0, fk1, gi, gi + half, o0, o1); bits = o0; }
        else           { tf2x32(fk0, fk1, gi - half, gi, o0, o1); bits = o1; }
      }
#endif
      float eps = __uint_as_float((bits >> 9) | 0x3f800000u) - 1.0f;
      double de = (double)eps;
      float thr = (float)log(de / (1.0 - de));   // -inf at eps==0: harmless
      ws_epsthr[flat] = make_float2(thr, eps);
    }
  }
}

// R7/R11 champion shape: 256 threads, ~25.5 KB LDS (6 blocks/CU), Bh in regs,
// Bl streamed from LDS, VGPR ~80. Do NOT grow LDS, merge phases, or pk-ify
// (R6/R8/R9/R12 all regressed on occupancy/VGPR).
template <int USE_PRE>
__global__ __launch_bounds__(256, 8) void sfis_main(
    const int*   __restrict__ x,
    const float* __restrict__ M,
    const float* __restrict__ w0,
    const float* __restrict__ w_table,
    const float* __restrict__ V_table,
    const float* __restrict__ Z_table,
    const float* __restrict__ b1,
    const float* __restrict__ W2,
    const float* __restrict__ b2,
    const unsigned short* __restrict__ ws_descs,
    const unsigned short* __restrict__ ws_w1hi,
    const unsigned short* __restrict__ ws_w1lo,
    const float2* __restrict__ epsthr,
    float* __restrict__ out,
    float* __restrict__ reg_partial) {
  __shared__ __align__(16) float V0s[17 * ROWP];  // row 16 = ones
  __shared__ __align__(16) float Z0s[17 * ROWP];
  __shared__ __align__(16) unsigned short W1loT[64 * WLOS];
  __shared__ __align__(4) unsigned short descs16[NSL];
  __shared__ float wts[NSL];
  __shared__ float t2s[NSL];
  __shared__ float W2s[64];
  __shared__ int xs[16];
  __shared__ float red8[8];
  __shared__ float wsum_s, w2sum_s;

  const int b   = blockIdx.x;
  const int tid = threadIdx.x;

  // ---- phase A: indices, ones rows, copy precomputed descs + W1lo table ----
  if (tid < 16) xs[tid] = x[b * 16 + tid];
  if (tid < 64) {
    W2s[tid] = W2[tid];
    V0s[16 * ROWP + tid] = 1.f;
    Z0s[16 * ROWP + tid] = 1.f;
  }
  for (int i = tid; i < NSL / 2; i += 256)    // 344 dwords
    ((uint32_t*)descs16)[i] = ((const uint32_t*)ws_descs)[i];
  for (int i = tid; i < 512; i += 256) {      // 64 rows x 8 chunks of 16B
    int n = i >> 3, ch = i & 7;
    *(u32x4*)((char*)W1loT + n * (WLOS * 2) + ch * 16) =
        *(const u32x4*)((const char*)ws_w1lo + n * 128 + ch * 16);
  }
  __syncthreads();

  // ---- phase C: V0f = M @ V, Z0f = M @ Z (from global; rows are L1-hot) ----
  if (tid == 0) {
    float s = 0.f, s2 = 0.f;
    for (int f = 0; f < 16; ++f) {
      float wv = w_table[xs[f]];
      s += wv; s2 += wv * wv;
    }
    wsum_s = s; w2sum_s = s2;
  }
  for (int idx = tid; idx < 1024; idx += 256) {
    int f = idx >> 6, d = idx & 63;
    float av = 0.f, az = 0.f;
    for (int g = 0; g < 16; ++g) {
      float m = M[f * 16 + g];          // wave-uniform -> s_load
      long off = (long)xs[g] * 64 + d;  // coalesced over d
      av = fmaf(m, V_table[off], av);
      az = fmaf(m, Z_table[off], az);
    }
    V0s[f * ROWP + d] = av;
    Z0s[f * ROWP + d] = az;
  }
  __syncthreads();

  // ---- phase D1: Wt / vsq on VALU; Wt -> LDS ----
  float v2acc = 0.f;
  for (int e0 = 0; e0 < 768; e0 += 256) {
    const int e = e0 + tid;
    const bool valid = (e < NE);
    uint32_t dsc = valid ? (uint32_t)descs16[e] : 0x4210u;
    const int oI = (int)(dsc & 31) * ROWP;
    const int oJ = (int)((dsc >> 5) & 31) * ROWP;
    const int oL = (int)((dsc >> 10) & 31) * ROWP;
    const int lvl = (dsc >> 15) & 1;

    float wt = 0.f, vsq = 0.f;
    for (int dq = 0; dq < 16; ++dq) {
      float4 a = *(const float4*)&V0s[oJ + (dq << 2)];
      float4 c = *(const float4*)&V0s[oL + (dq << 2)];
      float4 v = *(const float4*)&V0s[oI + (dq << 2)];
      float p0 = v.x * (a.x * c.x);
      float p1 = v.y * (a.y * c.y);
      float p2 = v.z * (a.z * c.z);
      float p3 = v.w * (a.w * c.w);
      wt  += p0 + p1 + p2 + p3;
      vsq += p0 * p0 + p1 * p1 + p2 * p2 + p3 * p3;
    }
    if (valid) wts[e] = wt;
    if (valid && lvl && (uint32_t)(e - L1N) < (uint32_t)KEEP2) v2acc += vsq;
  }

  // ---- phase D2: MLP hidden layer, bf16x3 MFMA GEMM (h = Z_sel@W1 + b1) ----
  // acc += Ah*Bh + Al*Bh + Ah*Bl. Ah = trunc(z), Al = trunc(z - Ah) [validated
  // R11]. Bh prebuilt fragments (16B loads); Bl streamed from W1loT LDS.
  {
    const int lane = tid & 63;
    const int wave = tid >> 6;
    const int col  = lane & 15;   // A-row / D-col / B-col within 16-tile
    const int kg   = lane >> 4;   // k-group: this lane's 8 contiguous k

    bf16x8 Bh[2][4];
#pragma unroll
    for (int ks = 0; ks < 2; ++ks)
#pragma unroll
      for (int c = 0; c < 4; ++c)
        Bh[ks][c] = *(const bf16x8*)&ws_w1hi[(c * 16 + col) * 64 + ks * 32 + kg * 8];
    float bv0 = b1[col], bv1 = b1[16 + col], bv2 = b1[32 + col], bv3 = b1[48 + col];

    for (int t = wave; t < NT; t += 4) {
      const int er = 16 * t + col;
      const uint32_t dsc = (uint32_t)descs16[er];
      const int oI = (int)(dsc & 31) * ROWP;
      const int oJ = (int)((dsc >> 5) & 31) * ROWP;
      const int oL = (int)((dsc >> 10) & 31) * ROWP;

      f32x4 acc[4];
      acc[0] = (f32x4){bv0, bv0, bv0, bv0};
      acc[1] = (f32x4){bv1, bv1, bv1, bv1};
      acc[2] = (f32x4){bv2, bv2, bv2, bv2};
      acc[3] = (f32x4){bv3, bv3, bv3, bv3};

#pragma unroll
      for (int ks = 0; ks < 2; ++ks) {
        const int kc = ks * 32 + kg * 8;
        float4 a0 = *(const float4*)&Z0s[oJ + kc];
        float4 c0 = *(const float4*)&Z0s[oL + kc];
        float4 z0 = *(const float4*)&Z0s[oI + kc];
        float4 a1 = *(const float4*)&Z0s[oJ + kc + 4];
        float4 c1 = *(const float4*)&Z0s[oL + kc + 4];
        float4 z1 = *(const float4*)&Z0s[oI + kc + 4];
        float z[8];
        z[0] = z0.x * (a0.x * c0.x);  z[1] = z0.y * (a0.y * c0.y);
        z[2] = z0.z * (a0.z * c0.z);  z[3] = z0.w * (a0.w * c0.w);
        z[4] = z1.x * (a1.x * c1.x);  z[5] = z1.y * (a1.y * c1.y);
        z[6] = z1.z * (a1.z * c1.z);  z[7] = z1.w * (a1.w * c1.w);

        ABfrag Ah, Al;
#pragma unroll
        for (int p = 0; p < 4; ++p) {
          uint32_t uz0 = __float_as_uint(z[2 * p]);
          uint32_t uz1 = __float_as_uint(z[2 * p + 1]);
          Ah.u[p] = __builtin_amdgcn_perm(uz1, uz0, 0x07060302u);
          float hf0 = __uint_as_float(uz0 & 0xffff0000u);
          float hf1 = __uint_as_float(uz1 & 0xffff0000u);
          uint32_t d0 = __float_as_uint(z[2 * p]     - hf0);
          uint32_t d1 = __float_as_uint(z[2 * p + 1] - hf1);
          Al.u[p] = __builtin_amdgcn_perm(d1, d0, 0x07060302u);  // truncation
        }
#pragma unroll
        for (int c = 0; c < 4; ++c)
          acc[c] = __builtin_amdgcn_mfma_f32_16x16x32_bf16(Ah.v, Bh[ks][c], acc[c], 0, 0, 0);
#pragma unroll
        for (int c = 0; c < 4; ++c)
          acc[c] = __builtin_amdgcn_mfma_f32_16x16x32_bf16(Al.v, Bh[ks][c], acc[c], 0, 0, 0);
#pragma unroll
        for (int c = 0; c < 4; ++c) {
          bf16x8 Blf = *(const bf16x8*)&W1loT[(c * 16 + col) * WLOS + ks * 32 + kg * 8];
          acc[c] = __builtin_amdgcn_mfma_f32_16x16x32_bf16(Ah.v, Blf, acc[c], 0, 0, 0);
        }
      }

      // second layer: t2 = relu(h) @ W2, reduced across the 16 cols
      float p0 = 0.f, p1 = 0.f, p2 = 0.f, p3 = 0.f;
#pragma unroll
      for (int c = 0; c < 4; ++c) {
        float w2v = W2s[c * 16 + col];
        p0 = fmaf(fmaxf(acc[c][0], 0.f), w2v, p0);
        p1 = fmaf(fmaxf(acc[c][1], 0.f), w2v, p1);
        p2 = fmaf(fmaxf(acc[c][2], 0.f), w2v, p2);
        p3 = fmaf(fmaxf(acc[c][3], 0.f), w2v, p3);
      }
#pragma unroll
      for (int m = 1; m < 16; m <<= 1) {
        p0 += __shfl_xor(p0, m, 16);
        p1 += __shfl_xor(p1, m, 16);
        p2 += __shfl_xor(p2, m, 16);
        p3 += __shfl_xor(p3, m, 16);
      }
      const int rb = 16 * t + kg * 4;   // D rows this lane-group owns
      if      (col == 0) t2s[rb + 0] = p0;
      else if (col == 1) t2s[rb + 1] = p1;
      else if (col == 2) t2s[rb + 2] = p2;
      else if (col == 3) t2s[rb + 3] = p3;
    }
  }
  __syncthreads();

  // ---- phase D3: gate. USE_PRE: t2 >= thr (precomputed logit) with exact
  // f64 fallback in the |t2-thr|<=1e-3 window (decisions == R11 path; the
  // f32-rounding hazard zone |thr|>4 is unreachable since |t2|<~0.2).
  // Fallback path (!USE_PRE): R11's threefry + guarded sigmoid, verbatim.
  const float b2v = b2[0];
  float yacc = 0.f;

  if (USE_PRE) {
    const float2* ebase = &epsthr[b * NSL];
    for (int e0 = 0; e0 < 768; e0 += 256) {
      const int e = e0 + tid;
      const bool valid = (e < NE);
      float t2 = (valid ? t2s[e] : 0.f) + b2v;
      float2 te = ebase[valid ? e : 0];
      bool gate;
      if (fabsf(t2 - te.x) > 1e-3f) {
        gate = (t2 >= te.x);
      } else {
        double ex = exp(-(double)t2);
        float pro = (float)(1.0 / (1.0 + ex));
        gate = (pro >= te.y);
      }
      if (valid && gate) yacc += wts[e];
    }
  } else {
    uint32_t fkA0, fkA1, fkB0, fkB1;   // fold_in(key(42), 0) and (.,1)
    tf2x32(0u, 42u, 0u, 0u, fkA0, fkA1);
    tf2x32(0u, 42u, 0u, 1u, fkB0, fkB1);
    for (int e0 = 0; e0 < 768; e0 += 256) {
      const int e = e0 + tid;
      const bool valid = (e < NE);
      uint32_t dsc = valid ? (uint32_t)descs16[e] : 0x4210u;
      const int lvl = (dsc >> 15) & 1;
      float t2 = (valid ? t2s[e] : 0.f) + b2v;

      uint32_t Lsz  = lvl ? (uint32_t)L2N : (uint32_t)L1N;
      uint32_t lidx = lvl ? (uint32_t)(e - L1N) : (uint32_t)e;
      uint32_t kk0  = lvl ? fkB0 : fkA0;
      uint32_t kk1  = lvl ? fkB1 : fkA1;
      uint32_t gi   = (uint32_t)b * Lsz + lidx;
      uint32_t o0, o1, bits;
#if THREEFRY_PARTITIONABLE
      tf2x32(kk0, kk1, 0u, gi, o0, o1);
      bits = o0 ^ o1;
#else
      {
        uint32_t half = Lsz * (NB / 2);
        if (gi < half) { tf2x32(kk0, kk1, gi, gi + half, o0, o1); bits = o0; }
        else           { tf2x32(kk0, kk1, gi - half, gi, o0, o1); bits = o1; }
      }
#endif
      float eps = __uint_as_float((bits >> 9) | 0x3f800000u) - 1.0f;
      float pf = 1.0f / (1.0f + __expf(-t2));
      bool gate;
      if (fabsf(pf - eps) > 1e-4f) {
        gate = (pf >= eps);
      } else {
        double ex = exp(-(double)t2);
        float pro = (float)(1.0 / (1.0 + ex));
        gate = (pro >= eps);
      }
      if (valid && gate) yacc += wts[e];
    }
  }

  // ---- phase E: wave-shuffle reduction, one barrier ----
  {
#pragma unroll
    for (int m = 32; m > 0; m >>= 1) {
      yacc  += __shfl_down(yacc, m, 64);
      v2acc += __shfl_down(v2acc, m, 64);
    }
    if ((tid & 63) == 0) {
      red8[tid >> 6]       = yacc;
      red8[4 + (tid >> 6)] = v2acc;
    }
    __syncthreads();
    if (tid == 0) {
      out[b] = w0[0] + wsum_s + ((red8[0] + red8[1]) + (red8[2] + red8[3]));
      reg_partial[b] = w2sum_s + ((red8[4] + red8[5]) + (red8[6] + red8[7]));
    }
  }
}

__global__ __launch_bounds__(256) void sfis_reduce(
    const float* __restrict__ reg_partial, float* __restrict__ out) {
  __shared__ float red[256];
  int tid = threadIdx.x;
  float s = 0.f;
  for (int i = tid; i < NB; i += 256) s += reg_partial[i];
  red[tid] = s;
  __syncthreads();
  for (int st = 128; st > 0; st >>= 1) {
    if (tid < st) red[tid] += red[tid + st];
    __syncthreads();
  }
  if (tid == 0) out[NB] = 1.0e-4f * red[0];  // BETA
}

extern "C" void kernel_launch(void* const* d_in, const int* in_sizes, int n_in,
                              void* d_out, int out_size, void* d_ws, size_t ws_size,
                              hipStream_t stream) {
  (void)in_sizes; (void)n_in; (void)out_size;
  const int*   x       = (const int*)  d_in[0];
  const float* M       = (const float*)d_in[1];
  const float* w0      = (const float*)d_in[2];
  const float* w_table = (const float*)d_in[3];
  const float* V_table = (const float*)d_in[4];
  const float* Z_table = (const float*)d_in[5];
  const float* W1      = (const float*)d_in[6];
  const float* b1      = (const float*)d_in[7];
  const float* W2      = (const float*)d_in[8];
  const float* b2      = (const float*)d_in[9];
  float* out  = (float*)d_out;

  // d_ws layout: [0,1376) descs | [2048,10240) W1hi | [10240,18432) W1lo |
  //              [20480,28672) reg partials | [32768, +11272192) epsthr
  unsigned short* ws_descs  = (unsigned short*)d_ws;
  unsigned short* ws_w1hi   = (unsigned short*)((char*)d_ws + 2048);
  unsigned short* ws_w1lo   = (unsigned short*)((char*)d_ws + 10240);
  float*          regp      = (float*)((char*)d_ws + 20480);
  float2*         ws_epsthr = (float2*)((char*)d_ws + 32768);

  const size_t need = 32768 + (size_t)NB * NSL * sizeof(float2);
  const bool pre = (ws_size >= need);
  const int eps_blocks = (NB * NSL + 255) / 256;   // 5504

  hipLaunchKernelGGL(sfis_setup, dim3(pre ? 17 + eps_blocks : 17), dim3(256),
                     0, stream, W1, ws_descs, ws_w1hi, ws_w1lo, ws_epsthr);
  if (pre) {
    hipLaunchKernelGGL((sfis_main<1>), dim3(NB), dim3(256), 0, stream,
                       x, M, w0, w_table, V_table, Z_table, b1, W2, b2,
                       ws_descs, ws_w1hi, ws_w1lo, ws_epsthr, out, regp);
  } else {
    hipLaunchKernelGGL((sfis_main<0>), dim3(NB), dim3(256), 0, stream,
                       x, M, w0, w_table, V_table, Z_table, b1, W2, b2,
                       ws_descs, ws_w1hi, ws_w1lo, ws_epsthr, out, regp);
  }
  hipLaunchKernelGGL(sfis_reduce, dim3(1), dim3(256), 0, stream, regp, out);
}

// Round 14
// 80.569 us; speedup vs baseline: 1.9596x; 1.1090x over previous
//
#include <hip/hip_runtime.h>
#include <stdint.h>
#include <math.h>

// SFIS: F=16, D=64, N=100000, B=2048, ORDER=3, BETA=1e-4, H=64
#define NB    2048
#define NE    680     // 120 pairs + 560 triples
#define L1N   120
#define L2N   560
#define KEEP2 455     // triples with A<=12 feed the regularizer
#define ROWP  68      // padded LDS row stride (floats) for V0s/Z0s
#define NT    43      // 16-row MFMA tiles covering 688 >= 680 rows
#define NSL   688     // NT*16
#define WLOS  72      // W1loT LDS row stride in ushorts (pad: bank-balanced b128)

#define THREEFRY_PARTITIONABLE 1

typedef __attribute__((ext_vector_type(8))) short bf16x8;
typedef __attribute__((ext_vector_type(4))) float f32x4;
typedef __attribute__((ext_vector_type(4))) uint32_t u32x4;

union ABfrag { bf16x8 v; uint32_t u[4]; };

__device__ __forceinline__ uint32_t rotl32(uint32_t v, uint32_t d) {
  return (v << d) | (v >> (32u - d));
}

// f32 -> bf16 bits, round-nearest-even (finite inputs only)
__device__ __forceinline__ uint32_t bf_rne(float f) {
  uint32_t u = __float_as_uint(f);
  return (u + 0x7fffu + ((u >> 16) & 1u)) >> 16;
}

// JAX threefry2x32 (jax/_src/prng.py), 20 rounds.
__device__ __forceinline__ void tf2x32(uint32_t k0, uint32_t k1,
                                       uint32_t c0, uint32_t c1,
                                       uint32_t &o0, uint32_t &o1) {
  uint32_t ks2 = k0 ^ k1 ^ 0x1BD11BDAu;
  uint32_t x0 = c0 + k0;
  uint32_t x1 = c1 + k1;
#define TF_R(r) { x0 += x1; x1 = rotl32(x1, r); x1 ^= x0; }
  TF_R(13) TF_R(15) TF_R(26) TF_R(6)
  x0 += k1;  x1 += ks2 + 1u;
  TF_R(17) TF_R(29) TF_R(16) TF_R(24)
  x0 += ks2; x1 += k0 + 2u;
  TF_R(13) TF_R(15) TF_R(26) TF_R(6)
  x0 += k0;  x1 += k1 + 3u;
  TF_R(17) TF_R(29) TF_R(16) TF_R(24)
  x0 += k1;  x1 += ks2 + 4u;
  TF_R(13) TF_R(15) TF_R(26) TF_R(6)
  x0 += ks2; x1 += k0 + 5u;
#undef TF_R
  o0 = x0; o1 = x1;
}

// One-shot per-launch precompute of block-invariant data (descs + W1 splits
// in fragment layout [n][k]). Grid = 17 blocks: 0..15 split W1, 16 builds
// descs. NOTE (R13 lesson): do NOT hoist the per-(b,e) threefry here — in
// main it hides under stalls (VALU 61% busy); as a dedicated dispatch it is
// exposed serial time and a net loss.
__global__ __launch_bounds__(256) void sfis_setup(
    const float* __restrict__ W1,
    unsigned short* __restrict__ ws_descs,   // [688]
    unsigned short* __restrict__ ws_w1hi,    // [64][64], n-major
    unsigned short* __restrict__ ws_w1lo) {  // [64][64], n-major
  const int bid = blockIdx.x, tid = threadIdx.x;
  if (bid == 16) {
    for (int e = tid; e < NSL; e += 256) {
      int fi, fj, fl, lvl;
      if (e < L1N) {                      // pair: V0f[a+1] * V0f[k]
        int a = 0;
        while ((a + 1) * (a + 2) / 2 <= e) ++a;
        int k = e - a * (a + 1) / 2;
        fi = a + 1; fj = k; fl = 16; lvl = 0;   // fl=16 -> ones row
      } else if (e < NE) {                // triple: V0f[A+2] * (V0f[a1+1]*V0f[k1])
        int e2 = e - L1N;
        int A = 0;
        while ((A + 1) * (A + 2) * (A + 3) / 6 <= e2) ++A;
        int k = e2 - A * (A + 1) * (A + 2) / 6;
        int a1 = 0;
        while ((a1 + 1) * (a1 + 2) / 2 <= k) ++a1;
        int k1 = k - a1 * (a1 + 1) / 2;
        fi = A + 2; fj = a1 + 1; fl = k1; lvl = 1;
      } else {                            // dummy rows 680..687 -> ones product
        fi = 16; fj = 16; fl = 16; lvl = 0;
      }
      ws_descs[e] = (unsigned short)((uint32_t)fi | ((uint32_t)fj << 5) |
                                     ((uint32_t)fl << 10) | ((uint32_t)lvl << 15));
    }
  } else {
    int i = bid * 256 + tid;            // i = k*64 + n over W1[64][64]
    int k = i >> 6, n = i & 63;
    float w = W1[i];
    uint32_t hb = bf_rne(w);
    float hf = __uint_as_float(hb << 16);
    uint32_t lb = bf_rne(w - hf);
    ws_w1hi[n * 64 + k] = (unsigned short)hb;
    ws_w1lo[n * 64 + k] = (unsigned short)lb;
  }
}

// R7/R11 champion shape: 256 threads, ~25.5 KB LDS, Bh in regs, Bl streamed
// from LDS, VGPR ~80, in-main threefry. Do NOT grow LDS, merge phases,
// pk-ify, or hoist eps (R6/R8/R9/R12/R13 all regressed).
__global__ __launch_bounds__(256, 8) void sfis_main(
    const int*   __restrict__ x,
    const float* __restrict__ M,
    const float* __restrict__ w0,
    const float* __restrict__ w_table,
    const float* __restrict__ V_table,
    const float* __restrict__ Z_table,
    const float* __restrict__ b1,
    const float* __restrict__ W2,
    const float* __restrict__ b2,
    const unsigned short* __restrict__ ws_descs,
    const unsigned short* __restrict__ ws_w1hi,
    const unsigned short* __restrict__ ws_w1lo,
    float* __restrict__ out,
    float* __restrict__ reg_partial) {
  __shared__ __align__(16) float V0s[17 * ROWP];  // row 16 = ones
  __shared__ __align__(16) float Z0s[17 * ROWP];
  __shared__ __align__(16) unsigned short W1loT[64 * WLOS];
  __shared__ __align__(4) unsigned short descs16[NSL];
  __shared__ float wts[NSL];
  __shared__ float t2s[NSL];
  __shared__ float W2s[64];
  __shared__ int xs[16];
  __shared__ float red8[8];
  __shared__ float wsum_s, w2sum_s;

  const int b   = blockIdx.x;
  const int tid = threadIdx.x;

  // ---- phase A: indices, ones rows, copy precomputed descs + W1lo table ----
  if (tid < 16) xs[tid] = x[b * 16 + tid];
  if (tid < 64) {
    W2s[tid] = W2[tid];
    V0s[16 * ROWP + tid] = 1.f;
    Z0s[16 * ROWP + tid] = 1.f;
  }
  for (int i = tid; i < NSL / 2; i += 256)    // 344 dwords
    ((uint32_t*)descs16)[i] = ((const uint32_t*)ws_descs)[i];
  for (int i = tid; i < 512; i += 256) {      // 64 rows x 8 chunks of 16B
    int n = i >> 3, ch = i & 7;
    *(u32x4*)((char*)W1loT + n * (WLOS * 2) + ch * 16) =
        *(const u32x4*)((const char*)ws_w1lo + n * 128 + ch * 16);
  }
  __syncthreads();

  // ---- phase C: V0f = M @ V, Z0f = M @ Z (from global; rows are L1-hot) ----
  if (tid == 0) {
    float s = 0.f, s2 = 0.f;
    for (int f = 0; f < 16; ++f) {
      float wv = w_table[xs[f]];
      s += wv; s2 += wv * wv;
    }
    wsum_s = s; w2sum_s = s2;
  }
  for (int idx = tid; idx < 1024; idx += 256) {
    int f = idx >> 6, d = idx & 63;
    float av = 0.f, az = 0.f;
    for (int g = 0; g < 16; ++g) {
      float m = M[f * 16 + g];          // wave-uniform -> s_load
      long off = (long)xs[g] * 64 + d;  // coalesced over d
      av = fmaf(m, V_table[off], av);
      az = fmaf(m, Z_table[off], az);
    }
    V0s[f * ROWP + d] = av;
    Z0s[f * ROWP + d] = az;
  }
  __syncthreads();

  // ---- phase D1: Wt / vsq on VALU; Wt -> LDS ----
  float v2acc = 0.f;
  for (int e0 = 0; e0 < 768; e0 += 256) {
    // Wave-uniform skip of fully-invalid waves (e0=512, wave base 192:
    // e in [704,768) all >= NE) — saves the whole dummy product loop.
    if (e0 + (tid & ~63) >= NE) continue;
    const int e = e0 + tid;
    const bool valid = (e < NE);
    uint32_t dsc = valid ? (uint32_t)descs16[e] : 0x4210u;
    const int oI = (int)(dsc & 31) * ROWP;
    const int oJ = (int)((dsc >> 5) & 31) * ROWP;
    const int oL = (int)((dsc >> 10) & 31) * ROWP;
    const int lvl = (dsc >> 15) & 1;

    float wt = 0.f, vsq = 0.f;
    for (int dq = 0; dq < 16; ++dq) {
      float4 a = *(const float4*)&V0s[oJ + (dq << 2)];
      float4 c = *(const float4*)&V0s[oL + (dq << 2)];
      float4 v = *(const float4*)&V0s[oI + (dq << 2)];
      float p0 = v.x * (a.x * c.x);
      float p1 = v.y * (a.y * c.y);
      float p2 = v.z * (a.z * c.z);
      float p3 = v.w * (a.w * c.w);
      wt  += p0 + p1 + p2 + p3;
      vsq += p0 * p0 + p1 * p1 + p2 * p2 + p3 * p3;
    }
    if (valid) wts[e] = wt;
    if (valid && lvl && (uint32_t)(e - L1N) < (uint32_t)KEEP2) v2acc += vsq;
  }

  // ---- phase D2: MLP hidden layer, bf16x3 MFMA GEMM (h = Z_sel@W1 + b1) ----
  // acc += Ah*Bh + Al*Bh + Ah*Bl. Ah = trunc(z), Al = trunc(z - Ah) [validated
  // R11]. Bh prebuilt fragments (16B loads); Bl streamed from W1loT LDS.
  {
    const int lane = tid & 63;
    const int wave = tid >> 6;
    const int col  = lane & 15;   // A-row / D-col / B-col within 16-tile
    const int kg   = lane >> 4;   // k-group: this lane's 8 contiguous k

    bf16x8 Bh[2][4];
#pragma unroll
    for (int ks = 0; ks < 2; ++ks)
#pragma unroll
      for (int c = 0; c < 4; ++c)
        Bh[ks][c] = *(const bf16x8*)&ws_w1hi[(c * 16 + col) * 64 + ks * 32 + kg * 8];
    float bv0 = b1[col], bv1 = b1[16 + col], bv2 = b1[32 + col], bv3 = b1[48 + col];

    for (int t = wave; t < NT; t += 4) {
      const int er = 16 * t + col;
      const uint32_t dsc = (uint32_t)descs16[er];
      const int oI = (int)(dsc & 31) * ROWP;
      const int oJ = (int)((dsc >> 5) & 31) * ROWP;
      const int oL = (int)((dsc >> 10) & 31) * ROWP;

      f32x4 acc[4];
      acc[0] = (f32x4){bv0, bv0, bv0, bv0};
      acc[1] = (f32x4){bv1, bv1, bv1, bv1};
      acc[2] = (f32x4){bv2, bv2, bv2, bv2};
      acc[3] = (f32x4){bv3, bv3, bv3, bv3};

#pragma unroll
      for (int ks = 0; ks < 2; ++ks) {
        const int kc = ks * 32 + kg * 8;
        float4 a0 = *(const float4*)&Z0s[oJ + kc];
        float4 c0 = *(const float4*)&Z0s[oL + kc];
        float4 z0 = *(const float4*)&Z0s[oI + kc];
        float4 a1 = *(const float4*)&Z0s[oJ + kc + 4];
        float4 c1 = *(const float4*)&Z0s[oL + kc + 4];
        float4 z1 = *(const float4*)&Z0s[oI + kc + 4];
        float z[8];
        z[0] = z0.x * (a0.x * c0.x);  z[1] = z0.y * (a0.y * c0.y);
        z[2] = z0.z * (a0.z * c0.z);  z[3] = z0.w * (a0.w * c0.w);
        z[4] = z1.x * (a1.x * c1.x);  z[5] = z1.y * (a1.y * c1.y);
        z[6] = z1.z * (a1.z * c1.z);  z[7] = z1.w * (a1.w * c1.w);

        ABfrag Ah, Al;
#pragma unroll
        for (int p = 0; p < 4; ++p) {
          uint32_t uz0 = __float_as_uint(z[2 * p]);
          uint32_t uz1 = __float_as_uint(z[2 * p + 1]);
          Ah.u[p] = __builtin_amdgcn_perm(uz1, uz0, 0x07060302u);
          float hf0 = __uint_as_float(uz0 & 0xffff0000u);
          float hf1 = __uint_as_float(uz1 & 0xffff0000u);
          uint32_t d0 = __float_as_uint(z[2 * p]     - hf0);
          uint32_t d1 = __float_as_uint(z[2 * p + 1] - hf1);
          Al.u[p] = __builtin_amdgcn_perm(d1, d0, 0x07060302u);  // truncation
        }
#pragma unroll
        for (int c = 0; c < 4; ++c)
          acc[c] = __builtin_amdgcn_mfma_f32_16x16x32_bf16(Ah.v, Bh[ks][c], acc[c], 0, 0, 0);
#pragma unroll
        for (int c = 0; c < 4; ++c)
          acc[c] = __builtin_amdgcn_mfma_f32_16x16x32_bf16(Al.v, Bh[ks][c], acc[c], 0, 0, 0);
#pragma unroll
        for (int c = 0; c < 4; ++c) {
          bf16x8 Blf = *(const bf16x8*)&W1loT[(c * 16 + col) * WLOS + ks * 32 + kg * 8];
          acc[c] = __builtin_amdgcn_mfma_f32_16x16x32_bf16(Ah.v, Blf, acc[c], 0, 0, 0);
        }
      }

      // second layer: t2 = relu(h) @ W2, reduced across the 16 cols
      float p0 = 0.f, p1 = 0.f, p2 = 0.f, p3 = 0.f;
#pragma unroll
      for (int c = 0; c < 4; ++c) {
        float w2v = W2s[c * 16 + col];
        p0 = fmaf(fmaxf(acc[c][0], 0.f), w2v, p0);
        p1 = fmaf(fmaxf(acc[c][1], 0.f), w2v, p1);
        p2 = fmaf(fmaxf(acc[c][2], 0.f), w2v, p2);
        p3 = fmaf(fmaxf(acc[c][3], 0.f), w2v, p3);
      }
#pragma unroll
      for (int m = 1; m < 16; m <<= 1) {
        p0 += __shfl_xor(p0, m, 16);
        p1 += __shfl_xor(p1, m, 16);
        p2 += __shfl_xor(p2, m, 16);
        p3 += __shfl_xor(p3, m, 16);
      }
      const int rb = 16 * t + kg * 4;   // D rows this lane-group owns
      if      (col == 0) t2s[rb + 0] = p0;
      else if (col == 1) t2s[rb + 1] = p1;
      else if (col == 2) t2s[rb + 2] = p2;
      else if (col == 3) t2s[rb + 3] = p3;
    }
  }
  __syncthreads();

  // ---- phase D3: eps (threefry), sigmoid (fast f32 + guarded f64), gate ----
  uint32_t fkA0, fkA1, fkB0, fkB1;   // fold_in(key(42), 0) and (.,1)
  tf2x32(0u, 42u, 0u, 0u, fkA0, fkA1);
  tf2x32(0u, 42u, 0u, 1u, fkB0, fkB1);
  const float b2v = b2[0];

  float yacc = 0.f;
  for (int e0 = 0; e0 < 768; e0 += 256) {
    if (e0 + (tid & ~63) >= NE) continue;    // wave-uniform skip (see D1)
    const int e = e0 + tid;
    const bool valid = (e < NE);
    uint32_t dsc = valid ? (uint32_t)descs16[e] : 0x4210u;
    const int lvl = (dsc >> 15) & 1;

    float t2 = (valid ? t2s[e] : 0.f) + b2v;

    uint32_t Lsz  = lvl ? (uint32_t)L2N : (uint32_t)L1N;
    uint32_t lidx = lvl ? (uint32_t)(e - L1N) : (uint32_t)e;
    uint32_t kk0  = lvl ? fkB0 : fkA0;
    uint32_t kk1  = lvl ? fkB1 : fkA1;
    uint32_t gi   = (uint32_t)b * Lsz + lidx;
    uint32_t o0, o1, bits;
#if THREEFRY_PARTITIONABLE
    tf2x32(kk0, kk1, 0u, gi, o0, o1);
    bits = o0 ^ o1;
#else
    {
      uint32_t half = Lsz * (NB / 2);
      if (gi < half) { tf2x32(kk0, kk1, gi, gi + half, o0, o1); bits = o0; }
      else           { tf2x32(kk0, kk1, gi - half, gi, o0, o1); bits = o1; }
    }
#endif
    float eps = __uint_as_float((bits >> 9) | 0x3f800000u) - 1.0f;

    // fast f32 sigmoid; exact f64 only in the ambiguity window. Decisions
    // identical to the pure-f64 path (validated R8-R13, absmax 0.0).
    float pf = 1.0f / (1.0f + __expf(-t2));
    bool gate;
    if (fabsf(pf - eps) > 1e-4f) {
      gate = (pf >= eps);
    } else {
      double ex = exp(-(double)t2);
      float pro = (float)(1.0 / (1.0 + ex));
      gate = (pro >= eps);
    }
    if (valid && gate) yacc += wts[e];
  }

  // ---- phase E: wave-shuffle reduction, one barrier ----
  {
#pragma unroll
    for (int m = 32; m > 0; m >>= 1) {
      yacc  += __shfl_down(yacc, m, 64);
      v2acc += __shfl_down(v2acc, m, 64);
    }
    if ((tid & 63) == 0) {
      red8[tid >> 6]       = yacc;
      red8[4 + (tid >> 6)] = v2acc;
    }
    __syncthreads();
    if (tid == 0) {
      out[b] = w0[0] + wsum_s + ((red8[0] + red8[1]) + (red8[2] + red8[3]));
      reg_partial[b] = w2sum_s + ((red8[4] + red8[5]) + (red8[6] + red8[7]));
    }
  }
}

__global__ __launch_bounds__(256) void sfis_reduce(
    const float* __restrict__ reg_partial, float* __restrict__ out) {
  __shared__ float red[256];
  int tid = threadIdx.x;
  float s = 0.f;
  for (int i = tid; i < NB; i += 256) s += reg_partial[i];
  red[tid] = s;
  __syncthreads();
  for (int st = 128; st > 0; st >>= 1) {
    if (tid < st) red[tid] += red[tid + st];
    __syncthreads();
  }
  if (tid == 0) out[NB] = 1.0e-4f * red[0];  // BETA
}

extern "C" void kernel_launch(void* const* d_in, const int* in_sizes, int n_in,
                              void* d_out, int out_size, void* d_ws, size_t ws_size,
                              hipStream_t stream) {
  (void)in_sizes; (void)n_in; (void)out_size; (void)ws_size;
  const int*   x       = (const int*)  d_in[0];
  const float* M       = (const float*)d_in[1];
  const float* w0      = (const float*)d_in[2];
  const float* w_table = (const float*)d_in[3];
  const float* V_table = (const float*)d_in[4];
  const float* Z_table = (const float*)d_in[5];
  const float* W1      = (const float*)d_in[6];
  const float* b1      = (const float*)d_in[7];
  const float* W2      = (const float*)d_in[8];
  const float* b2      = (const float*)d_in[9];
  float* out  = (float*)d_out;

  // d_ws layout: [0,1376) descs | [2048,10240) W1hi | [10240,18432) W1lo |
  //              [20480, +8KB) reg partials
  unsigned short* ws_descs = (unsigned short*)d_ws;
  unsigned short* ws_w1hi  = (unsigned short*)((char*)d_ws + 2048);
  unsigned short* ws_w1lo  = (unsigned short*)((char*)d_ws + 10240);
  float*          regp     = (float*)((char*)d_ws + 20480);

  hipLaunchKernelGGL(sfis_setup, dim3(17), dim3(256), 0, stream,
                     W1, ws_descs, ws_w1hi, ws_w1lo);
  hipLaunchKernelGGL(sfis_main, dim3(NB), dim3(256), 0, stream,
                     x, M, w0, w_table, V_table, Z_table, b1, W2, b2,
                     ws_descs, ws_w1hi, ws_w1lo, out, regp);
  hipLaunchKernelGGL(sfis_reduce, dim3(1), dim3(256), 0, stream, regp, out);
}

// Round 15
// 80.171 us; speedup vs baseline: 1.9694x; 1.0050x over previous
//
#include <hip/hip_runtime.h>
#include <stdint.h>
#include <math.h>

// SFIS: F=16, D=64, N=100000, B=2048, ORDER=3, BETA=1e-4, H=64
#define NB    2048
#define NE    680     // 120 pairs + 560 triples
#define L1N   120
#define L2N   560
#define KEEP2 455     // triples with A<=12 feed the regularizer
#define ROWP  68      // padded LDS row stride (floats) for V0s/Z0s
#define NT    43      // 16-row MFMA tiles covering 688 >= 680 rows
#define NSL   688     // NT*16
#define WLOS  72      // W1loT LDS row stride in ushorts (pad: bank-balanced b128)

#define THREEFRY_PARTITIONABLE 1

typedef __attribute__((ext_vector_type(8))) short bf16x8;
typedef __attribute__((ext_vector_type(4))) float f32x4;
typedef __attribute__((ext_vector_type(4))) uint32_t u32x4;

union ABfrag { bf16x8 v; uint32_t u[4]; };

__device__ __forceinline__ uint32_t rotl32(uint32_t v, uint32_t d) {
  return (v << d) | (v >> (32u - d));
}

// f32 -> bf16 bits, round-nearest-even (finite inputs only)
__device__ __forceinline__ uint32_t bf_rne(float f) {
  uint32_t u = __float_as_uint(f);
  return (u + 0x7fffu + ((u >> 16) & 1u)) >> 16;
}

// JAX threefry2x32 (jax/_src/prng.py), 20 rounds.
__device__ __forceinline__ void tf2x32(uint32_t k0, uint32_t k1,
                                       uint32_t c0, uint32_t c1,
                                       uint32_t &o0, uint32_t &o1) {
  uint32_t ks2 = k0 ^ k1 ^ 0x1BD11BDAu;
  uint32_t x0 = c0 + k0;
  uint32_t x1 = c1 + k1;
#define TF_R(r) { x0 += x1; x1 = rotl32(x1, r); x1 ^= x0; }
  TF_R(13) TF_R(15) TF_R(26) TF_R(6)
  x0 += k1;  x1 += ks2 + 1u;
  TF_R(17) TF_R(29) TF_R(16) TF_R(24)
  x0 += ks2; x1 += k0 + 2u;
  TF_R(13) TF_R(15) TF_R(26) TF_R(6)
  x0 += k0;  x1 += k1 + 3u;
  TF_R(17) TF_R(29) TF_R(16) TF_R(24)
  x0 += k1;  x1 += ks2 + 4u;
  TF_R(13) TF_R(15) TF_R(26) TF_R(6)
  x0 += ks2; x1 += k0 + 5u;
#undef TF_R
  o0 = x0; o1 = x1;
}

// One-shot per-launch precompute of block-invariant data (descs + W1 splits
// in fragment layout [n][k]) + zero the regularizer accumulator out[NB].
// Grid = 17 blocks: 0..15 split W1, 16 builds descs. NOTE (R13 lesson): do
// NOT hoist the per-(b,e) threefry here — in main it hides under stalls; as
// a dedicated dispatch it is exposed serial time and a net loss.
__global__ __launch_bounds__(256) void sfis_setup(
    const float* __restrict__ W1,
    unsigned short* __restrict__ ws_descs,   // [688]
    unsigned short* __restrict__ ws_w1hi,    // [64][64], n-major
    unsigned short* __restrict__ ws_w1lo,    // [64][64], n-major
    float* __restrict__ out) {
  const int bid = blockIdx.x, tid = threadIdx.x;
  if (bid == 16) {
    if (tid == 0) out[NB] = 0.f;   // main blocks atomicAdd the regularizer
    for (int e = tid; e < NSL; e += 256) {
      int fi, fj, fl, lvl;
      if (e < L1N) {                      // pair: V0f[a+1] * V0f[k]
        int a = 0;
        while ((a + 1) * (a + 2) / 2 <= e) ++a;
        int k = e - a * (a + 1) / 2;
        fi = a + 1; fj = k; fl = 16; lvl = 0;   // fl=16 -> ones row
      } else if (e < NE) {                // triple: V0f[A+2] * (V0f[a1+1]*V0f[k1])
        int e2 = e - L1N;
        int A = 0;
        while ((A + 1) * (A + 2) * (A + 3) / 6 <= e2) ++A;
        int k = e2 - A * (A + 1) * (A + 2) / 6;
        int a1 = 0;
        while ((a1 + 1) * (a1 + 2) / 2 <= k) ++a1;
        int k1 = k - a1 * (a1 + 1) / 2;
        fi = A + 2; fj = a1 + 1; fl = k1; lvl = 1;
      } else {                            // dummy rows 680..687 -> ones product
        fi = 16; fj = 16; fl = 16; lvl = 0;
      }
      ws_descs[e] = (unsigned short)((uint32_t)fi | ((uint32_t)fj << 5) |
                                     ((uint32_t)fl << 10) | ((uint32_t)lvl << 15));
    }
  } else {
    int i = bid * 256 + tid;            // i = k*64 + n over W1[64][64]
    int k = i >> 6, n = i & 63;
    float w = W1[i];
    uint32_t hb = bf_rne(w);
    float hf = __uint_as_float(hb << 16);
    uint32_t lb = bf_rne(w - hf);
    ws_w1hi[n * 64 + k] = (unsigned short)hb;
    ws_w1lo[n * 64 + k] = (unsigned short)lb;
  }
}

// R7/R11 champion shape: 256 threads, ~25.5 KB LDS, Bh in regs, Bl streamed
// from LDS, VGPR ~80, in-main threefry. Do NOT grow LDS, merge phases,
// pk-ify, or hoist eps (R6/R8/R9/R12/R13 all regressed).
__global__ __launch_bounds__(256, 8) void sfis_main(
    const int*   __restrict__ x,
    const float* __restrict__ M,
    const float* __restrict__ w0,
    const float* __restrict__ w_table,
    const float* __restrict__ V_table,
    const float* __restrict__ Z_table,
    const float* __restrict__ b1,
    const float* __restrict__ W2,
    const float* __restrict__ b2,
    const unsigned short* __restrict__ ws_descs,
    const unsigned short* __restrict__ ws_w1hi,
    const unsigned short* __restrict__ ws_w1lo,
    float* __restrict__ out) {
  __shared__ __align__(16) float V0s[17 * ROWP];  // row 16 = ones
  __shared__ __align__(16) float Z0s[17 * ROWP];
  __shared__ __align__(16) unsigned short W1loT[64 * WLOS];
  __shared__ __align__(4) unsigned short descs16[NSL];
  __shared__ float wts[NSL];
  __shared__ float t2s[NSL];
  __shared__ float W2s[64];
  __shared__ int xs[16];
  __shared__ float red8[8];
  __shared__ float wsum_s, w2sum_s;

  const int b   = blockIdx.x;
  const int tid = threadIdx.x;

  // ---- phase A: indices, ones rows, copy precomputed descs + W1lo table ----
  if (tid < 16) xs[tid] = x[b * 16 + tid];
  if (tid < 64) {
    W2s[tid] = W2[tid];
    V0s[16 * ROWP + tid] = 1.f;
    Z0s[16 * ROWP + tid] = 1.f;
  }
  for (int i = tid; i < NSL / 2; i += 256)    // 344 dwords
    ((uint32_t*)descs16)[i] = ((const uint32_t*)ws_descs)[i];
  for (int i = tid; i < 512; i += 256) {      // 64 rows x 8 chunks of 16B
    int n = i >> 3, ch = i & 7;
    *(u32x4*)((char*)W1loT + n * (WLOS * 2) + ch * 16) =
        *(const u32x4*)((const char*)ws_w1lo + n * 128 + ch * 16);
  }
  __syncthreads();

  // ---- phase C: V0f = M @ V, Z0f = M @ Z (from global; rows are L1-hot) ----
  if (tid == 0) {
    float s = 0.f, s2 = 0.f;
    for (int f = 0; f < 16; ++f) {
      float wv = w_table[xs[f]];
      s += wv; s2 += wv * wv;
    }
    wsum_s = s; w2sum_s = s2;
  }
  for (int idx = tid; idx < 1024; idx += 256) {
    int f = idx >> 6, d = idx & 63;
    float av = 0.f, az = 0.f;
    for (int g = 0; g < 16; ++g) {
      float m = M[f * 16 + g];          // wave-uniform -> s_load
      long off = (long)xs[g] * 64 + d;  // coalesced over d
      av = fmaf(m, V_table[off], av);
      az = fmaf(m, Z_table[off], az);
    }
    V0s[f * ROWP + d] = av;
    Z0s[f * ROWP + d] = az;
  }
  __syncthreads();

  // ---- phase D1: Wt / vsq on VALU; Wt -> LDS ----
  float v2acc = 0.f;
  for (int e0 = 0; e0 < 768; e0 += 256) {
    // Wave-uniform skip of fully-invalid waves (e in [704,768) all >= NE).
    if (e0 + (tid & ~63) >= NE) continue;
    const int e = e0 + tid;
    const bool valid = (e < NE);
    uint32_t dsc = valid ? (uint32_t)descs16[e] : 0x4210u;
    const int oI = (int)(dsc & 31) * ROWP;
    const int oJ = (int)((dsc >> 5) & 31) * ROWP;
    const int oL = (int)((dsc >> 10) & 31) * ROWP;
    const int lvl = (dsc >> 15) & 1;

    float wt = 0.f, vsq = 0.f;
    for (int dq = 0; dq < 16; ++dq) {
      float4 a = *(const float4*)&V0s[oJ + (dq << 2)];
      float4 c = *(const float4*)&V0s[oL + (dq << 2)];
      float4 v = *(const float4*)&V0s[oI + (dq << 2)];
      float p0 = v.x * (a.x * c.x);
      float p1 = v.y * (a.y * c.y);
      float p2 = v.z * (a.z * c.z);
      float p3 = v.w * (a.w * c.w);
      wt  += p0 + p1 + p2 + p3;
      vsq += p0 * p0 + p1 * p1 + p2 * p2 + p3 * p3;
    }
    if (valid) wts[e] = wt;
    if (valid && lvl && (uint32_t)(e - L1N) < (uint32_t)KEEP2) v2acc += vsq;
  }

  // ---- phase D2: MLP hidden layer, bf16x3 MFMA GEMM (h = Z_sel@W1 + b1) ----
  // acc += Ah*Bh + Al*Bh + Ah*Bl. Ah = trunc(z), Al = trunc(z - Ah) [validated
  // R11]. Bh prebuilt fragments (16B loads); Bl streamed from W1loT LDS.
  {
    const int lane = tid & 63;
    const int wave = tid >> 6;
    const int col  = lane & 15;   // A-row / D-col / B-col within 16-tile
    const int kg   = lane >> 4;   // k-group: this lane's 8 contiguous k

    bf16x8 Bh[2][4];
#pragma unroll
    for (int ks = 0; ks < 2; ++ks)
#pragma unroll
      for (int c = 0; c < 4; ++c)
        Bh[ks][c] = *(const bf16x8*)&ws_w1hi[(c * 16 + col) * 64 + ks * 32 + kg * 8];
    float bv0 = b1[col], bv1 = b1[16 + col], bv2 = b1[32 + col], bv3 = b1[48 + col];

    for (int t = wave; t < NT; t += 4) {
      const int er = 16 * t + col;
      const uint32_t dsc = (uint32_t)descs16[er];
      const int oI = (int)(dsc & 31) * ROWP;
      const int oJ = (int)((dsc >> 5) & 31) * ROWP;
      const int oL = (int)((dsc >> 10) & 31) * ROWP;

      f32x4 acc[4];
      acc[0] = (f32x4){bv0, bv0, bv0, bv0};
      acc[1] = (f32x4){bv1, bv1, bv1, bv1};
      acc[2] = (f32x4){bv2, bv2, bv2, bv2};
      acc[3] = (f32x4){bv3, bv3, bv3, bv3};

#pragma unroll
      for (int ks = 0; ks < 2; ++ks) {
        const int kc = ks * 32 + kg * 8;
        float4 a0 = *(const float4*)&Z0s[oJ + kc];
        float4 c0 = *(const float4*)&Z0s[oL + kc];
        float4 z0 = *(const float4*)&Z0s[oI + kc];
        float4 a1 = *(const float4*)&Z0s[oJ + kc + 4];
        float4 c1 = *(const float4*)&Z0s[oL + kc + 4];
        float4 z1 = *(const float4*)&Z0s[oI + kc + 4];
        float z[8];
        z[0] = z0.x * (a0.x * c0.x);  z[1] = z0.y * (a0.y * c0.y);
        z[2] = z0.z * (a0.z * c0.z);  z[3] = z0.w * (a0.w * c0.w);
        z[4] = z1.x * (a1.x * c1.x);  z[5] = z1.y * (a1.y * c1.y);
        z[6] = z1.z * (a1.z * c1.z);  z[7] = z1.w * (a1.w * c1.w);

        ABfrag Ah, Al;
#pragma unroll
        for (int p = 0; p < 4; ++p) {
          uint32_t uz0 = __float_as_uint(z[2 * p]);
          uint32_t uz1 = __float_as_uint(z[2 * p + 1]);
          Ah.u[p] = __builtin_amdgcn_perm(uz1, uz0, 0x07060302u);
          float hf0 = __uint_as_float(uz0 & 0xffff0000u);
          float hf1 = __uint_as_float(uz1 & 0xffff0000u);
          uint32_t d0 = __float_as_uint(z[2 * p]     - hf0);
          uint32_t d1 = __float_as_uint(z[2 * p + 1] - hf1);
          Al.u[p] = __builtin_amdgcn_perm(d1, d0, 0x07060302u);  // truncation
        }
#pragma unroll
        for (int c = 0; c < 4; ++c)
          acc[c] = __builtin_amdgcn_mfma_f32_16x16x32_bf16(Ah.v, Bh[ks][c], acc[c], 0, 0, 0);
#pragma unroll
        for (int c = 0; c < 4; ++c)
          acc[c] = __builtin_amdgcn_mfma_f32_16x16x32_bf16(Al.v, Bh[ks][c], acc[c], 0, 0, 0);
#pragma unroll
        for (int c = 0; c < 4; ++c) {
          bf16x8 Blf = *(const bf16x8*)&W1loT[(c * 16 + col) * WLOS + ks * 32 + kg * 8];
          acc[c] = __builtin_amdgcn_mfma_f32_16x16x32_bf16(Ah.v, Blf, acc[c], 0, 0, 0);
        }
      }

      // second layer: t2 = relu(h) @ W2, reduced across the 16 cols
      float p0 = 0.f, p1 = 0.f, p2 = 0.f, p3 = 0.f;
#pragma unroll
      for (int c = 0; c < 4; ++c) {
        float w2v = W2s[c * 16 + col];
        p0 = fmaf(fmaxf(acc[c][0], 0.f), w2v, p0);
        p1 = fmaf(fmaxf(acc[c][1], 0.f), w2v, p1);
        p2 = fmaf(fmaxf(acc[c][2], 0.f), w2v, p2);
        p3 = fmaf(fmaxf(acc[c][3], 0.f), w2v, p3);
      }
#pragma unroll
      for (int m = 1; m < 16; m <<= 1) {
        p0 += __shfl_xor(p0, m, 16);
        p1 += __shfl_xor(p1, m, 16);
        p2 += __shfl_xor(p2, m, 16);
        p3 += __shfl_xor(p3, m, 16);
      }
      const int rb = 16 * t + kg * 4;   // D rows this lane-group owns
      if      (col == 0) t2s[rb + 0] = p0;
      else if (col == 1) t2s[rb + 1] = p1;
      else if (col == 2) t2s[rb + 2] = p2;
      else if (col == 3) t2s[rb + 3] = p3;
    }
  }
  __syncthreads();

  // ---- phase D3: eps (threefry), sigmoid (fast f32 + guarded f64), gate ----
  uint32_t fkA0, fkA1, fkB0, fkB1;   // fold_in(key(42), 0) and (.,1)
  tf2x32(0u, 42u, 0u, 0u, fkA0, fkA1);
  tf2x32(0u, 42u, 0u, 1u, fkB0, fkB1);
  const float b2v = b2[0];

  float yacc = 0.f;
  for (int e0 = 0; e0 < 768; e0 += 256) {
    if (e0 + (tid & ~63) >= NE) continue;    // wave-uniform skip (see D1)
    const int e = e0 + tid;
    const bool valid = (e < NE);
    uint32_t dsc = valid ? (uint32_t)descs16[e] : 0x4210u;
    const int lvl = (dsc >> 15) & 1;

    float t2 = (valid ? t2s[e] : 0.f) + b2v;

    uint32_t Lsz  = lvl ? (uint32_t)L2N : (uint32_t)L1N;
    uint32_t lidx = lvl ? (uint32_t)(e - L1N) : (uint32_t)e;
    uint32_t kk0  = lvl ? fkB0 : fkA0;
    uint32_t kk1  = lvl ? fkB1 : fkA1;
    uint32_t gi   = (uint32_t)b * Lsz + lidx;
    uint32_t o0, o1, bits;
#if THREEFRY_PARTITIONABLE
    tf2x32(kk0, kk1, 0u, gi, o0, o1);
    bits = o0 ^ o1;
#else
    {
      uint32_t half = Lsz * (NB / 2);
      if (gi < half) { tf2x32(kk0, kk1, gi, gi + half, o0, o1); bits = o0; }
      else           { tf2x32(kk0, kk1, gi - half, gi, o0, o1); bits = o1; }
    }
#endif
    float eps = __uint_as_float((bits >> 9) | 0x3f800000u) - 1.0f;

    // fast f32 sigmoid; exact f64 only in the ambiguity window. Decisions
    // identical to the pure-f64 path (validated R8-R14, absmax 0.0).
    float pf = 1.0f / (1.0f + __expf(-t2));
    bool gate;
    if (fabsf(pf - eps) > 1e-4f) {
      gate = (pf >= eps);
    } else {
      double ex = exp(-(double)t2);
      float pro = (float)(1.0 / (1.0 + ex));
      gate = (pro >= eps);
    }
    if (valid && gate) yacc += wts[e];
  }

  // ---- phase E: wave-shuffle reduction + fused regularizer atomic ----
  {
#pragma unroll
    for (int m = 32; m > 0; m >>= 1) {
      yacc  += __shfl_down(yacc, m, 64);
      v2acc += __shfl_down(v2acc, m, 64);
    }
    if ((tid & 63) == 0) {
      red8[tid >> 6]       = yacc;
      red8[4 + (tid >> 6)] = v2acc;
    }
    __syncthreads();
    if (tid == 0) {
      out[b] = w0[0] + wsum_s + ((red8[0] + red8[1]) + (red8[2] + red8[3]));
      float v2 = w2sum_s + ((red8[4] + red8[5]) + (red8[6] + red8[7]));
      // device-scope atomic; out[NB] zeroed by sfis_setup each launch.
      // Order nondeterminism perturbs the sum at ~1e-10 rel — << threshold.
      atomicAdd(&out[NB], 1.0e-4f * v2);   // BETA
    }
  }
}

extern "C" void kernel_launch(void* const* d_in, const int* in_sizes, int n_in,
                              void* d_out, int out_size, void* d_ws, size_t ws_size,
                              hipStream_t stream) {
  (void)in_sizes; (void)n_in; (void)out_size; (void)ws_size;
  const int*   x       = (const int*)  d_in[0];
  const float* M       = (const float*)d_in[1];
  const float* w0      = (const float*)d_in[2];
  const float* w_table = (const float*)d_in[3];
  const float* V_table = (const float*)d_in[4];
  const float* Z_table = (const float*)d_in[5];
  const float* W1      = (const float*)d_in[6];
  const float* b1      = (const float*)d_in[7];
  const float* W2      = (const float*)d_in[8];
  const float* b2      = (const float*)d_in[9];
  float* out  = (float*)d_out;

  // d_ws layout: [0,1376) descs | [2048,10240) W1hi | [10240,18432) W1lo
  unsigned short* ws_descs = (unsigned short*)d_ws;
  unsigned short* ws_w1hi  = (unsigned short*)((char*)d_ws + 2048);
  unsigned short* ws_w1lo  = (unsigned short*)((char*)d_ws + 10240);

  hipLaunchKernelGGL(sfis_setup, dim3(17), dim3(256), 0, stream,
                     W1, ws_descs, ws_w1hi, ws_w1lo, out);
  hipLaunchKernelGGL(sfis_main, dim3(NB), dim3(256), 0, stream,
                     x, M, w0, w_table, V_table, Z_table, b1, W2, b2,
                     ws_descs, ws_w1hi, ws_w1lo, out);
}

// Round 16
// 79.208 us; speedup vs baseline: 1.9933x; 1.0122x over previous
//
#include <hip/hip_runtime.h>
#include <stdint.h>
#include <math.h>

// SFIS: F=16, D=64, N=100000, B=2048, ORDER=3, BETA=1e-4, H=64
#define NB    2048
#define NE    680     // 120 pairs + 560 triples
#define L1N   120
#define L2N   560
#define KEEP2 455     // triples with A<=12 feed the regularizer
#define ROWP  68      // padded LDS row stride (floats) for V0s/Z0s
#define NT    43      // 16-row MFMA tiles covering 688 >= 680 rows
#define NSL   688     // NT*16
#define WLOS  72      // W1loT LDS row stride in ushorts (pad: bank-balanced b128)

#define THREEFRY_PARTITIONABLE 1

typedef __attribute__((ext_vector_type(8))) short bf16x8;
typedef __attribute__((ext_vector_type(4))) float f32x4;
typedef __attribute__((ext_vector_type(2))) float f32x2;
typedef __attribute__((ext_vector_type(4))) uint32_t u32x4;

union ABfrag { bf16x8 v; uint32_t u[4]; };

__device__ __forceinline__ uint32_t rotl32(uint32_t v, uint32_t d) {
  return (v << d) | (v >> (32u - d));
}

// f32 -> bf16 bits, round-nearest-even (finite inputs only)
__device__ __forceinline__ uint32_t bf_rne(float f) {
  uint32_t u = __float_as_uint(f);
  return (u + 0x7fffu + ((u >> 16) & 1u)) >> 16;
}

// JAX threefry2x32 (jax/_src/prng.py), 20 rounds.
__device__ __forceinline__ void tf2x32(uint32_t k0, uint32_t k1,
                                       uint32_t c0, uint32_t c1,
                                       uint32_t &o0, uint32_t &o1) {
  uint32_t ks2 = k0 ^ k1 ^ 0x1BD11BDAu;
  uint32_t x0 = c0 + k0;
  uint32_t x1 = c1 + k1;
#define TF_R(r) { x0 += x1; x1 = rotl32(x1, r); x1 ^= x0; }
  TF_R(13) TF_R(15) TF_R(26) TF_R(6)
  x0 += k1;  x1 += ks2 + 1u;
  TF_R(17) TF_R(29) TF_R(16) TF_R(24)
  x0 += ks2; x1 += k0 + 2u;
  TF_R(13) TF_R(15) TF_R(26) TF_R(6)
  x0 += k0;  x1 += k1 + 3u;
  TF_R(17) TF_R(29) TF_R(16) TF_R(24)
  x0 += k1;  x1 += ks2 + 4u;
  TF_R(13) TF_R(15) TF_R(26) TF_R(6)
  x0 += ks2; x1 += k0 + 5u;
#undef TF_R
  o0 = x0; o1 = x1;
}

// One-shot per-launch precompute of block-invariant data (descs + W1 splits
// in fragment layout [n][k]) + zero the regularizer accumulator out[NB].
// Grid = 17 blocks: 0..15 split W1, 16 builds descs. NOTE (R13 lesson): do
// NOT hoist the per-(b,e) threefry here — in main it hides under stalls; as
// a dedicated dispatch it is exposed serial time and a net loss.
__global__ __launch_bounds__(256) void sfis_setup(
    const float* __restrict__ W1,
    unsigned short* __restrict__ ws_descs,   // [688]
    unsigned short* __restrict__ ws_w1hi,    // [64][64], n-major
    unsigned short* __restrict__ ws_w1lo,    // [64][64], n-major
    float* __restrict__ out) {
  const int bid = blockIdx.x, tid = threadIdx.x;
  if (bid == 16) {
    if (tid == 0) out[NB] = 0.f;   // main blocks atomicAdd the regularizer
    for (int e = tid; e < NSL; e += 256) {
      int fi, fj, fl, lvl;
      if (e < L1N) {                      // pair: V0f[a+1] * V0f[k]
        int a = 0;
        while ((a + 1) * (a + 2) / 2 <= e) ++a;
        int k = e - a * (a + 1) / 2;
        fi = a + 1; fj = k; fl = 16; lvl = 0;   // fl=16 -> ones row
      } else if (e < NE) {                // triple: V0f[A+2] * (V0f[a1+1]*V0f[k1])
        int e2 = e - L1N;
        int A = 0;
        while ((A + 1) * (A + 2) * (A + 3) / 6 <= e2) ++A;
        int k = e2 - A * (A + 1) * (A + 2) / 6;
        int a1 = 0;
        while ((a1 + 1) * (a1 + 2) / 2 <= k) ++a1;
        int k1 = k - a1 * (a1 + 1) / 2;
        fi = A + 2; fj = a1 + 1; fl = k1; lvl = 1;
      } else {                            // dummy rows 680..687 -> ones product
        fi = 16; fj = 16; fl = 16; lvl = 0;
      }
      ws_descs[e] = (unsigned short)((uint32_t)fi | ((uint32_t)fj << 5) |
                                     ((uint32_t)fl << 10) | ((uint32_t)lvl << 15));
    }
  } else {
    int i = bid * 256 + tid;            // i = k*64 + n over W1[64][64]
    int k = i >> 6, n = i & 63;
    float w = W1[i];
    uint32_t hb = bf_rne(w);
    float hf = __uint_as_float(hb << 16);
    uint32_t lb = bf_rne(w - hf);
    ws_w1hi[n * 64 + k] = (unsigned short)hb;
    ws_w1lo[n * 64 + k] = (unsigned short)lb;
  }
}

// R7/R11 champion shape: 256 threads, ~25.5 KB LDS, Bh in regs, Bl streamed
// from LDS, VGPR ~80, in-main threefry. Do NOT grow LDS, merge phases, or
// hoist eps (R6/R8/R9/R13 regressed). R16: pk-f32 scoped to D1 ONLY (R12's
// global pk blew VGPR to 176; D1's body is short-lived — numerics already
// validated by R12's absmax 0.0).
__global__ __launch_bounds__(256, 8) void sfis_main(
    const int*   __restrict__ x,
    const float* __restrict__ M,
    const float* __restrict__ w0,
    const float* __restrict__ w_table,
    const float* __restrict__ V_table,
    const float* __restrict__ Z_table,
    const float* __restrict__ b1,
    const float* __restrict__ W2,
    const float* __restrict__ b2,
    const unsigned short* __restrict__ ws_descs,
    const unsigned short* __restrict__ ws_w1hi,
    const unsigned short* __restrict__ ws_w1lo,
    float* __restrict__ out) {
  __shared__ __align__(16) float V0s[17 * ROWP];  // row 16 = ones
  __shared__ __align__(16) float Z0s[17 * ROWP];
  __shared__ __align__(16) unsigned short W1loT[64 * WLOS];
  __shared__ __align__(4) unsigned short descs16[NSL];
  __shared__ float wts[NSL];
  __shared__ float t2s[NSL];
  __shared__ float W2s[64];
  __shared__ int xs[16];
  __shared__ float red8[8];
  __shared__ float wsum_s, w2sum_s;

  const int b   = blockIdx.x;
  const int tid = threadIdx.x;

  // ---- phase A: indices, ones rows, copy precomputed descs + W1lo table ----
  if (tid < 16) xs[tid] = x[b * 16 + tid];
  if (tid < 64) {
    W2s[tid] = W2[tid];
    V0s[16 * ROWP + tid] = 1.f;
    Z0s[16 * ROWP + tid] = 1.f;
  }
  for (int i = tid; i < NSL / 2; i += 256)    // 344 dwords
    ((uint32_t*)descs16)[i] = ((const uint32_t*)ws_descs)[i];
  for (int i = tid; i < 512; i += 256) {      // 64 rows x 8 chunks of 16B
    int n = i >> 3, ch = i & 7;
    *(u32x4*)((char*)W1loT + n * (WLOS * 2) + ch * 16) =
        *(const u32x4*)((const char*)ws_w1lo + n * 128 + ch * 16);
  }
  __syncthreads();

  // ---- phase C: V0f = M @ V, Z0f = M @ Z (from global; rows are L1-hot) ----
  if (tid == 0) {
    float s = 0.f, s2 = 0.f;
    for (int f = 0; f < 16; ++f) {
      float wv = w_table[xs[f]];
      s += wv; s2 += wv * wv;
    }
    wsum_s = s; w2sum_s = s2;
  }
  for (int idx = tid; idx < 1024; idx += 256) {
    int f = idx >> 6, d = idx & 63;
    float av = 0.f, az = 0.f;
    for (int g = 0; g < 16; ++g) {
      float m = M[f * 16 + g];          // wave-uniform -> s_load
      long off = (long)xs[g] * 64 + d;  // coalesced over d
      av = fmaf(m, V_table[off], av);
      az = fmaf(m, Z_table[off], az);
    }
    V0s[f * ROWP + d] = av;
    Z0s[f * ROWP + d] = az;
  }
  __syncthreads();

  // ---- phase D1: Wt / vsq on VALU (pk-f32 pairs, R12-validated numerics) ----
  float v2acc = 0.f;
  for (int e0 = 0; e0 < 768; e0 += 256) {
    // Wave-uniform skip of fully-invalid waves (e in [704,768) all >= NE).
    if (e0 + (tid & ~63) >= NE) continue;
    const int e = e0 + tid;
    const bool valid = (e < NE);
    uint32_t dsc = valid ? (uint32_t)descs16[e] : 0x4210u;
    const int oI = (int)(dsc & 31) * ROWP;
    const int oJ = (int)((dsc >> 5) & 31) * ROWP;
    const int oL = (int)((dsc >> 10) & 31) * ROWP;
    const int lvl = (dsc >> 15) & 1;

    f32x2 wt2 = {0.f, 0.f}, vs2 = {0.f, 0.f};
    for (int dq = 0; dq < 16; ++dq) {
      float4 a = *(const float4*)&V0s[oJ + (dq << 2)];
      float4 c = *(const float4*)&V0s[oL + (dq << 2)];
      float4 v = *(const float4*)&V0s[oI + (dq << 2)];
      f32x2 p01 = (f32x2){v.x, v.y} * ((f32x2){a.x, a.y} * (f32x2){c.x, c.y});
      f32x2 p23 = (f32x2){v.z, v.w} * ((f32x2){a.z, a.w} * (f32x2){c.z, c.w});
      wt2 += p01;
      wt2 += p23;
      vs2 = __builtin_elementwise_fma(p01, p01, vs2);
      vs2 = __builtin_elementwise_fma(p23, p23, vs2);
    }
    if (valid) wts[e] = wt2.x + wt2.y;
    if (valid && lvl && (uint32_t)(e - L1N) < (uint32_t)KEEP2)
      v2acc += vs2.x + vs2.y;
  }

  // ---- phase D2: MLP hidden layer, bf16x3 MFMA GEMM (h = Z_sel@W1 + b1) ----
  // acc += Ah*Bh + Al*Bh + Ah*Bl. Ah = trunc(z), Al = trunc(z - Ah) [validated
  // R11]. Bh prebuilt fragments (16B loads); Bl streamed from W1loT LDS.
  // SCALAR arithmetic here on purpose — R12's pk-ification of this region
  // forced VGPR 80->176.
  {
    const int lane = tid & 63;
    const int wave = tid >> 6;
    const int col  = lane & 15;   // A-row / D-col / B-col within 16-tile
    const int kg   = lane >> 4;   // k-group: this lane's 8 contiguous k

    bf16x8 Bh[2][4];
#pragma unroll
    for (int ks = 0; ks < 2; ++ks)
#pragma unroll
      for (int c = 0; c < 4; ++c)
        Bh[ks][c] = *(const bf16x8*)&ws_w1hi[(c * 16 + col) * 64 + ks * 32 + kg * 8];
    float bv0 = b1[col], bv1 = b1[16 + col], bv2 = b1[32 + col], bv3 = b1[48 + col];

    for (int t = wave; t < NT; t += 4) {
      const int er = 16 * t + col;
      const uint32_t dsc = (uint32_t)descs16[er];
      const int oI = (int)(dsc & 31) * ROWP;
      const int oJ = (int)((dsc >> 5) & 31) * ROWP;
      const int oL = (int)((dsc >> 10) & 31) * ROWP;

      f32x4 acc[4];
      acc[0] = (f32x4){bv0, bv0, bv0, bv0};
      acc[1] = (f32x4){bv1, bv1, bv1, bv1};
      acc[2] = (f32x4){bv2, bv2, bv2, bv2};
      acc[3] = (f32x4){bv3, bv3, bv3, bv3};

#pragma unroll
      for (int ks = 0; ks < 2; ++ks) {
        const int kc = ks * 32 + kg * 8;
        float4 a0 = *(const float4*)&Z0s[oJ + kc];
        float4 c0 = *(const float4*)&Z0s[oL + kc];
        float4 z0 = *(const float4*)&Z0s[oI + kc];
        float4 a1 = *(const float4*)&Z0s[oJ + kc + 4];
        float4 c1 = *(const float4*)&Z0s[oL + kc + 4];
        float4 z1 = *(const float4*)&Z0s[oI + kc + 4];
        float z[8];
        z[0] = z0.x * (a0.x * c0.x);  z[1] = z0.y * (a0.y * c0.y);
        z[2] = z0.z * (a0.z * c0.z);  z[3] = z0.w * (a0.w * c0.w);
        z[4] = z1.x * (a1.x * c1.x);  z[5] = z1.y * (a1.y * c1.y);
        z[6] = z1.z * (a1.z * c1.z);  z[7] = z1.w * (a1.w * c1.w);

        ABfrag Ah, Al;
#pragma unroll
        for (int p = 0; p < 4; ++p) {
          uint32_t uz0 = __float_as_uint(z[2 * p]);
          uint32_t uz1 = __float_as_uint(z[2 * p + 1]);
          Ah.u[p] = __builtin_amdgcn_perm(uz1, uz0, 0x07060302u);
          float hf0 = __uint_as_float(uz0 & 0xffff0000u);
          float hf1 = __uint_as_float(uz1 & 0xffff0000u);
          uint32_t d0 = __float_as_uint(z[2 * p]     - hf0);
          uint32_t d1 = __float_as_uint(z[2 * p + 1] - hf1);
          Al.u[p] = __builtin_amdgcn_perm(d1, d0, 0x07060302u);  // truncation
        }
#pragma unroll
        for (int c = 0; c < 4; ++c)
          acc[c] = __builtin_amdgcn_mfma_f32_16x16x32_bf16(Ah.v, Bh[ks][c], acc[c], 0, 0, 0);
#pragma unroll
        for (int c = 0; c < 4; ++c)
          acc[c] = __builtin_amdgcn_mfma_f32_16x16x32_bf16(Al.v, Bh[ks][c], acc[c], 0, 0, 0);
#pragma unroll
        for (int c = 0; c < 4; ++c) {
          bf16x8 Blf = *(const bf16x8*)&W1loT[(c * 16 + col) * WLOS + ks * 32 + kg * 8];
          acc[c] = __builtin_amdgcn_mfma_f32_16x16x32_bf16(Ah.v, Blf, acc[c], 0, 0, 0);
        }
      }

      // second layer: t2 = relu(h) @ W2, reduced across the 16 cols
      float p0 = 0.f, p1 = 0.f, p2 = 0.f, p3 = 0.f;
#pragma unroll
      for (int c = 0; c < 4; ++c) {
        float w2v = W2s[c * 16 + col];
        p0 = fmaf(fmaxf(acc[c][0], 0.f), w2v, p0);
        p1 = fmaf(fmaxf(acc[c][1], 0.f), w2v, p1);
        p2 = fmaf(fmaxf(acc[c][2], 0.f), w2v, p2);
        p3 = fmaf(fmaxf(acc[c][3], 0.f), w2v, p3);
      }
#pragma unroll
      for (int m = 1; m < 16; m <<= 1) {
        p0 += __shfl_xor(p0, m, 16);
        p1 += __shfl_xor(p1, m, 16);
        p2 += __shfl_xor(p2, m, 16);
        p3 += __shfl_xor(p3, m, 16);
      }
      const int rb = 16 * t + kg * 4;   // D rows this lane-group owns
      if      (col == 0) t2s[rb + 0] = p0;
      else if (col == 1) t2s[rb + 1] = p1;
      else if (col == 2) t2s[rb + 2] = p2;
      else if (col == 3) t2s[rb + 3] = p3;
    }
  }
  __syncthreads();

  // ---- phase D3: eps (threefry), sigmoid (fast f32 + guarded f64), gate ----
  uint32_t fkA0, fkA1, fkB0, fkB1;   // fold_in(key(42), 0) and (.,1)
  tf2x32(0u, 42u, 0u, 0u, fkA0, fkA1);
  tf2x32(0u, 42u, 0u, 1u, fkB0, fkB1);
  const float b2v = b2[0];

  float yacc = 0.f;
  for (int e0 = 0; e0 < 768; e0 += 256) {
    if (e0 + (tid & ~63) >= NE) continue;    // wave-uniform skip (see D1)
    const int e = e0 + tid;
    const bool valid = (e < NE);
    uint32_t dsc = valid ? (uint32_t)descs16[e] : 0x4210u;
    const int lvl = (dsc >> 15) & 1;

    float t2 = (valid ? t2s[e] : 0.f) + b2v;

    uint32_t Lsz  = lvl ? (uint32_t)L2N : (uint32_t)L1N;
    uint32_t lidx = lvl ? (uint32_t)(e - L1N) : (uint32_t)e;
    uint32_t kk0  = lvl ? fkB0 : fkA0;
    uint32_t kk1  = lvl ? fkB1 : fkA1;
    uint32_t gi   = (uint32_t)b * Lsz + lidx;
    uint32_t o0, o1, bits;
#if THREEFRY_PARTITIONABLE
    tf2x32(kk0, kk1, 0u, gi, o0, o1);
    bits = o0 ^ o1;
#else
    {
      uint32_t half = Lsz * (NB / 2);
      if (gi < half) { tf2x32(kk0, kk1, gi, gi + half, o0, o1); bits = o0; }
      else           { tf2x32(kk0, kk1, gi - half, gi, o0, o1); bits = o1; }
    }
#endif
    float eps = __uint_as_float((bits >> 9) | 0x3f800000u) - 1.0f;

    // fast f32 sigmoid; exact f64 only in the ambiguity window. Decisions
    // identical to the pure-f64 path (validated R8-R15, absmax 0.0).
    float pf = 1.0f / (1.0f + __expf(-t2));
    bool gate;
    if (fabsf(pf - eps) > 1e-4f) {
      gate = (pf >= eps);
    } else {
      double ex = exp(-(double)t2);
      float pro = (float)(1.0 / (1.0 + ex));
      gate = (pro >= eps);
    }
    if (valid && gate) yacc += wts[e];
  }

  // ---- phase E: wave-shuffle reduction + fused regularizer atomic ----
  {
#pragma unroll
    for (int m = 32; m > 0; m >>= 1) {
      yacc  += __shfl_down(yacc, m, 64);
      v2acc += __shfl_down(v2acc, m, 64);
    }
    if ((tid & 63) == 0) {
      red8[tid >> 6]       = yacc;
      red8[4 + (tid >> 6)] = v2acc;
    }
    __syncthreads();
    if (tid == 0) {
      out[b] = w0[0] + wsum_s + ((red8[0] + red8[1]) + (red8[2] + red8[3]));
      float v2 = w2sum_s + ((red8[4] + red8[5]) + (red8[6] + red8[7]));
      // device-scope atomic; out[NB] zeroed by sfis_setup each launch.
      // Order nondeterminism perturbs the sum at ~1e-10 rel — << threshold.
      atomicAdd(&out[NB], 1.0e-4f * v2);   // BETA
    }
  }
}

extern "C" void kernel_launch(void* const* d_in, const int* in_sizes, int n_in,
                              void* d_out, int out_size, void* d_ws, size_t ws_size,
                              hipStream_t stream) {
  (void)in_sizes; (void)n_in; (void)out_size; (void)ws_size;
  const int*   x       = (const int*)  d_in[0];
  const float* M       = (const float*)d_in[1];
  const float* w0      = (const float*)d_in[2];
  const float* w_table = (const float*)d_in[3];
  const float* V_table = (const float*)d_in[4];
  const float* Z_table = (const float*)d_in[5];
  const float* W1      = (const float*)d_in[6];
  const float* b1      = (const float*)d_in[7];
  const float* W2      = (const float*)d_in[8];
  const float* b2      = (const float*)d_in[9];
  float* out  = (float*)d_out;

  // d_ws layout: [0,1376) descs | [2048,10240) W1hi | [10240,18432) W1lo
  unsigned short* ws_descs = (unsigned short*)d_ws;
  unsigned short* ws_w1hi  = (unsigned short*)((char*)d_ws + 2048);
  unsigned short* ws_w1lo  = (unsigned short*)((char*)d_ws + 10240);

  hipLaunchKernelGGL(sfis_setup, dim3(17), dim3(256), 0, stream,
                     W1, ws_descs, ws_w1hi, ws_w1lo, out);
  hipLaunchKernelGGL(sfis_main, dim3(NB), dim3(256), 0, stream,
                     x, M, w0, w_table, V_table, Z_table, b1, W2, b2,
                     ws_descs, ws_w1hi, ws_w1lo, out);
}

// Round 17
// 78.982 us; speedup vs baseline: 1.9990x; 1.0029x over previous
//
#include <hip/hip_runtime.h>
#include <stdint.h>
#include <math.h>

// SFIS: F=16, D=64, N=100000, B=2048, ORDER=3, BETA=1e-4, H=64
#define NB    2048
#define NE    680     // 120 pairs + 560 triples
#define L1N   120
#define L2N   560
#define KEEP2 455     // triples with A<=12 feed the regularizer
#define ROWP  68      // padded LDS row stride (floats) for V0s/Z0s
#define NT    43      // 16-row MFMA tiles covering 688 >= 680 rows
#define NSL   688     // NT*16
#define WLOS  72      // W1loT LDS row stride in ushorts (pad: bank-balanced b128)

#define THREEFRY_PARTITIONABLE 1

typedef __attribute__((ext_vector_type(8))) short bf16x8;
typedef __attribute__((ext_vector_type(4))) float f32x4;
typedef __attribute__((ext_vector_type(2))) float f32x2;
typedef __attribute__((ext_vector_type(4))) uint32_t u32x4;

union ABfrag { bf16x8 v; uint32_t u[4]; };

__device__ __forceinline__ uint32_t rotl32(uint32_t v, uint32_t d) {
  return (v << d) | (v >> (32u - d));
}

// f32 -> bf16 bits, round-nearest-even (finite inputs only)
__device__ __forceinline__ uint32_t bf_rne(float f) {
  uint32_t u = __float_as_uint(f);
  return (u + 0x7fffu + ((u >> 16) & 1u)) >> 16;
}

// JAX threefry2x32 (jax/_src/prng.py), 20 rounds.
__device__ __forceinline__ void tf2x32(uint32_t k0, uint32_t k1,
                                       uint32_t c0, uint32_t c1,
                                       uint32_t &o0, uint32_t &o1) {
  uint32_t ks2 = k0 ^ k1 ^ 0x1BD11BDAu;
  uint32_t x0 = c0 + k0;
  uint32_t x1 = c1 + k1;
#define TF_R(r) { x0 += x1; x1 = rotl32(x1, r); x1 ^= x0; }
  TF_R(13) TF_R(15) TF_R(26) TF_R(6)
  x0 += k1;  x1 += ks2 + 1u;
  TF_R(17) TF_R(29) TF_R(16) TF_R(24)
  x0 += ks2; x1 += k0 + 2u;
  TF_R(13) TF_R(15) TF_R(26) TF_R(6)
  x0 += k0;  x1 += k1 + 3u;
  TF_R(17) TF_R(29) TF_R(16) TF_R(24)
  x0 += k1;  x1 += ks2 + 4u;
  TF_R(13) TF_R(15) TF_R(26) TF_R(6)
  x0 += ks2; x1 += k0 + 5u;
#undef TF_R
  o0 = x0; o1 = x1;
}

// One-shot per-launch precompute of block-invariant data (descs + W1 splits
// in fragment layout [n][k]) + zero the regularizer accumulator out[NB].
// Grid = 17 blocks: 0..15 split W1, 16 builds descs. NOTE (R13 lesson): do
// NOT hoist the per-(b,e) threefry here — in main it hides under stalls; as
// a dedicated dispatch it is exposed serial time and a net loss.
__global__ __launch_bounds__(256) void sfis_setup(
    const float* __restrict__ W1,
    unsigned short* __restrict__ ws_descs,   // [688]
    unsigned short* __restrict__ ws_w1hi,    // [64][64], n-major
    unsigned short* __restrict__ ws_w1lo,    // [64][64], n-major
    float* __restrict__ out) {
  const int bid = blockIdx.x, tid = threadIdx.x;
  if (bid == 16) {
    if (tid == 0) out[NB] = 0.f;   // main blocks atomicAdd the regularizer
    for (int e = tid; e < NSL; e += 256) {
      int fi, fj, fl, lvl;
      if (e < L1N) {                      // pair: V0f[a+1] * V0f[k]
        int a = 0;
        while ((a + 1) * (a + 2) / 2 <= e) ++a;
        int k = e - a * (a + 1) / 2;
        fi = a + 1; fj = k; fl = 16; lvl = 0;   // fl=16 -> ones row
      } else if (e < NE) {                // triple: V0f[A+2] * (V0f[a1+1]*V0f[k1])
        int e2 = e - L1N;
        int A = 0;
        while ((A + 1) * (A + 2) * (A + 3) / 6 <= e2) ++A;
        int k = e2 - A * (A + 1) * (A + 2) / 6;
        int a1 = 0;
        while ((a1 + 1) * (a1 + 2) / 2 <= k) ++a1;
        int k1 = k - a1 * (a1 + 1) / 2;
        fi = A + 2; fj = a1 + 1; fl = k1; lvl = 1;
      } else {                            // dummy rows 680..687 -> ones product
        fi = 16; fj = 16; fl = 16; lvl = 0;
      }
      ws_descs[e] = (unsigned short)((uint32_t)fi | ((uint32_t)fj << 5) |
                                     ((uint32_t)fl << 10) | ((uint32_t)lvl << 15));
    }
  } else {
    int i = bid * 256 + tid;            // i = k*64 + n over W1[64][64]
    int k = i >> 6, n = i & 63;
    float w = W1[i];
    uint32_t hb = bf_rne(w);
    float hf = __uint_as_float(hb << 16);
    uint32_t lb = bf_rne(w - hf);
    ws_w1hi[n * 64 + k] = (unsigned short)hb;
    ws_w1lo[n * 64 + k] = (unsigned short)lb;
  }
}

// R7/R11 champion shape: 256 threads, ~25.5 KB LDS, Bh in regs, Bl streamed
// from LDS, VGPR ~72, in-main threefry. Do NOT grow LDS, merge phases, or
// hoist eps (R6/R8/R9/R13 regressed). pk-f32 is scoped to D1 (R16, −8 VGPR),
// phase C, and the D2 epilogue — NEVER the D2 MFMA/z-split region (R12:
// VGPR 80->176). All pk numerics element-order-identical (R12 absmax 0.0).
__global__ __launch_bounds__(256, 8) void sfis_main(
    const int*   __restrict__ x,
    const float* __restrict__ M,
    const float* __restrict__ w0,
    const float* __restrict__ w_table,
    const float* __restrict__ V_table,
    const float* __restrict__ Z_table,
    const float* __restrict__ b1,
    const float* __restrict__ W2,
    const float* __restrict__ b2,
    const unsigned short* __restrict__ ws_descs,
    const unsigned short* __restrict__ ws_w1hi,
    const unsigned short* __restrict__ ws_w1lo,
    float* __restrict__ out) {
  __shared__ __align__(16) float V0s[17 * ROWP];  // row 16 = ones
  __shared__ __align__(16) float Z0s[17 * ROWP];
  __shared__ __align__(16) unsigned short W1loT[64 * WLOS];
  __shared__ __align__(4) unsigned short descs16[NSL];
  __shared__ float wts[NSL];
  __shared__ float t2s[NSL];
  __shared__ float W2s[64];
  __shared__ int xs[16];
  __shared__ float red8[8];
  __shared__ float wsum_s, w2sum_s;

  const int b   = blockIdx.x;
  const int tid = threadIdx.x;

  // ---- phase A: indices, ones rows, copy precomputed descs + W1lo table ----
  if (tid < 16) xs[tid] = x[b * 16 + tid];
  if (tid < 64) {
    W2s[tid] = W2[tid];
    V0s[16 * ROWP + tid] = 1.f;
    Z0s[16 * ROWP + tid] = 1.f;
  }
  for (int i = tid; i < NSL / 2; i += 256)    // 344 dwords
    ((uint32_t*)descs16)[i] = ((const uint32_t*)ws_descs)[i];
  for (int i = tid; i < 512; i += 256) {      // 64 rows x 8 chunks of 16B
    int n = i >> 3, ch = i & 7;
    *(u32x4*)((char*)W1loT + n * (WLOS * 2) + ch * 16) =
        *(const u32x4*)((const char*)ws_w1lo + n * 128 + ch * 16);
  }
  __syncthreads();

  // ---- phase C: V0f = M @ V, Z0f = M @ Z (paired V/Z pk_fma) ----
  if (tid == 0) {
    float s = 0.f, s2 = 0.f;
    for (int f = 0; f < 16; ++f) {
      float wv = w_table[xs[f]];
      s += wv; s2 += wv * wv;
    }
    wsum_s = s; w2sum_s = s2;
  }
  for (int idx = tid; idx < 1024; idx += 256) {
    int f = idx >> 6, d = idx & 63;
    f32x2 acc2 = {0.f, 0.f};
    for (int g = 0; g < 16; ++g) {
      float m = M[f * 16 + g];          // wave-uniform -> s_load
      long off = (long)xs[g] * 64 + d;  // coalesced over d
      f32x2 vz = {V_table[off], Z_table[off]};
      acc2 = __builtin_elementwise_fma((f32x2){m, m}, vz, acc2);
    }
    V0s[f * ROWP + d] = acc2.x;
    Z0s[f * ROWP + d] = acc2.y;
  }
  __syncthreads();

  // ---- phase D1: Wt / vsq on VALU (pk-f32 pairs, R12-validated numerics) ----
  float v2acc = 0.f;
  for (int e0 = 0; e0 < 768; e0 += 256) {
    // Wave-uniform skip of fully-invalid waves (e in [704,768) all >= NE).
    if (e0 + (tid & ~63) >= NE) continue;
    const int e = e0 + tid;
    const bool valid = (e < NE);
    uint32_t dsc = valid ? (uint32_t)descs16[e] : 0x4210u;
    const int oI = (int)(dsc & 31) * ROWP;
    const int oJ = (int)((dsc >> 5) & 31) * ROWP;
    const int oL = (int)((dsc >> 10) & 31) * ROWP;
    const int lvl = (dsc >> 15) & 1;

    f32x2 wt2 = {0.f, 0.f}, vs2 = {0.f, 0.f};
    for (int dq = 0; dq < 16; ++dq) {
      float4 a = *(const float4*)&V0s[oJ + (dq << 2)];
      float4 c = *(const float4*)&V0s[oL + (dq << 2)];
      float4 v = *(const float4*)&V0s[oI + (dq << 2)];
      f32x2 p01 = (f32x2){v.x, v.y} * ((f32x2){a.x, a.y} * (f32x2){c.x, c.y});
      f32x2 p23 = (f32x2){v.z, v.w} * ((f32x2){a.z, a.w} * (f32x2){c.z, c.w});
      wt2 += p01;
      wt2 += p23;
      vs2 = __builtin_elementwise_fma(p01, p01, vs2);
      vs2 = __builtin_elementwise_fma(p23, p23, vs2);
    }
    if (valid) wts[e] = wt2.x + wt2.y;
    if (valid && lvl && (uint32_t)(e - L1N) < (uint32_t)KEEP2)
      v2acc += vs2.x + vs2.y;
  }

  // ---- phase D2: MLP hidden layer, bf16x3 MFMA GEMM (h = Z_sel@W1 + b1) ----
  // acc += Ah*Bh + Al*Bh + Ah*Bl. Ah = trunc(z), Al = trunc(z - Ah) [validated
  // R11]. Bh prebuilt fragments (16B loads); Bl streamed from W1loT LDS.
  // SCALAR z-split arithmetic on purpose — R12's pk-ification of this region
  // forced VGPR 80->176.
  {
    const int lane = tid & 63;
    const int wave = tid >> 6;
    const int col  = lane & 15;   // A-row / D-col / B-col within 16-tile
    const int kg   = lane >> 4;   // k-group: this lane's 8 contiguous k

    bf16x8 Bh[2][4];
#pragma unroll
    for (int ks = 0; ks < 2; ++ks)
#pragma unroll
      for (int c = 0; c < 4; ++c)
        Bh[ks][c] = *(const bf16x8*)&ws_w1hi[(c * 16 + col) * 64 + ks * 32 + kg * 8];
    float bv0 = b1[col], bv1 = b1[16 + col], bv2 = b1[32 + col], bv3 = b1[48 + col];

    for (int t = wave; t < NT; t += 4) {
      const int er = 16 * t + col;
      const uint32_t dsc = (uint32_t)descs16[er];
      const int oI = (int)(dsc & 31) * ROWP;
      const int oJ = (int)((dsc >> 5) & 31) * ROWP;
      const int oL = (int)((dsc >> 10) & 31) * ROWP;

      f32x4 acc[4];
      acc[0] = (f32x4){bv0, bv0, bv0, bv0};
      acc[1] = (f32x4){bv1, bv1, bv1, bv1};
      acc[2] = (f32x4){bv2, bv2, bv2, bv2};
      acc[3] = (f32x4){bv3, bv3, bv3, bv3};

#pragma unroll
      for (int ks = 0; ks < 2; ++ks) {
        const int kc = ks * 32 + kg * 8;
        float4 a0 = *(const float4*)&Z0s[oJ + kc];
        float4 c0 = *(const float4*)&Z0s[oL + kc];
        float4 z0 = *(const float4*)&Z0s[oI + kc];
        float4 a1 = *(const float4*)&Z0s[oJ + kc + 4];
        float4 c1 = *(const float4*)&Z0s[oL + kc + 4];
        float4 z1 = *(const float4*)&Z0s[oI + kc + 4];
        float z[8];
        z[0] = z0.x * (a0.x * c0.x);  z[1] = z0.y * (a0.y * c0.y);
        z[2] = z0.z * (a0.z * c0.z);  z[3] = z0.w * (a0.w * c0.w);
        z[4] = z1.x * (a1.x * c1.x);  z[5] = z1.y * (a1.y * c1.y);
        z[6] = z1.z * (a1.z * c1.z);  z[7] = z1.w * (a1.w * c1.w);

        ABfrag Ah, Al;
#pragma unroll
        for (int p = 0; p < 4; ++p) {
          uint32_t uz0 = __float_as_uint(z[2 * p]);
          uint32_t uz1 = __float_as_uint(z[2 * p + 1]);
          Ah.u[p] = __builtin_amdgcn_perm(uz1, uz0, 0x07060302u);
          float hf0 = __uint_as_float(uz0 & 0xffff0000u);
          float hf1 = __uint_as_float(uz1 & 0xffff0000u);
          uint32_t d0 = __float_as_uint(z[2 * p]     - hf0);
          uint32_t d1 = __float_as_uint(z[2 * p + 1] - hf1);
          Al.u[p] = __builtin_amdgcn_perm(d1, d0, 0x07060302u);  // truncation
        }
#pragma unroll
        for (int c = 0; c < 4; ++c)
          acc[c] = __builtin_amdgcn_mfma_f32_16x16x32_bf16(Ah.v, Bh[ks][c], acc[c], 0, 0, 0);
#pragma unroll
        for (int c = 0; c < 4; ++c)
          acc[c] = __builtin_amdgcn_mfma_f32_16x16x32_bf16(Al.v, Bh[ks][c], acc[c], 0, 0, 0);
#pragma unroll
        for (int c = 0; c < 4; ++c) {
          bf16x8 Blf = *(const bf16x8*)&W1loT[(c * 16 + col) * WLOS + ks * 32 + kg * 8];
          acc[c] = __builtin_amdgcn_mfma_f32_16x16x32_bf16(Ah.v, Blf, acc[c], 0, 0, 0);
        }
      }

      // second layer: t2 = relu(h) @ W2 (pk max/fma), reduce across 16 cols
      const f32x2 zero2 = {0.f, 0.f};
      f32x2 q01 = {0.f, 0.f}, q23 = {0.f, 0.f};
#pragma unroll
      for (int c = 0; c < 4; ++c) {
        float w2v = W2s[c * 16 + col];
        f32x2 w22 = {w2v, w2v};
        f32x2 h01 = {acc[c][0], acc[c][1]};
        f32x2 h23 = {acc[c][2], acc[c][3]};
        q01 = __builtin_elementwise_fma(__builtin_elementwise_max(h01, zero2), w22, q01);
        q23 = __builtin_elementwise_fma(__builtin_elementwise_max(h23, zero2), w22, q23);
      }
      float p0 = q01.x, p1 = q01.y, p2 = q23.x, p3 = q23.y;
#pragma unroll
      for (int m = 1; m < 16; m <<= 1) {
        p0 += __shfl_xor(p0, m, 16);
        p1 += __shfl_xor(p1, m, 16);
        p2 += __shfl_xor(p2, m, 16);
        p3 += __shfl_xor(p3, m, 16);
      }
      const int rb = 16 * t + kg * 4;   // D rows this lane-group owns
      if      (col == 0) t2s[rb + 0] = p0;
      else if (col == 1) t2s[rb + 1] = p1;
      else if (col == 2) t2s[rb + 2] = p2;
      else if (col == 3) t2s[rb + 3] = p3;
    }
  }
  __syncthreads();

  // ---- phase D3: eps (threefry), sigmoid (fast f32 + guarded f64), gate ----
  uint32_t fkA0, fkA1, fkB0, fkB1;   // fold_in(key(42), 0) and (.,1)
  tf2x32(0u, 42u, 0u, 0u, fkA0, fkA1);
  tf2x32(0u, 42u, 0u, 1u, fkB0, fkB1);
  const float b2v = b2[0];

  float yacc = 0.f;
  for (int e0 = 0; e0 < 768; e0 += 256) {
    if (e0 + (tid & ~63) >= NE) continue;    // wave-uniform skip (see D1)
    const int e = e0 + tid;
    const bool valid = (e < NE);
    uint32_t dsc = valid ? (uint32_t)descs16[e] : 0x4210u;
    const int lvl = (dsc >> 15) & 1;

    float t2 = (valid ? t2s[e] : 0.f) + b2v;

    uint32_t Lsz  = lvl ? (uint32_t)L2N : (uint32_t)L1N;
    uint32_t lidx = lvl ? (uint32_t)(e - L1N) : (uint32_t)e;
    uint32_t kk0  = lvl ? fkB0 : fkA0;
    uint32_t kk1  = lvl ? fkB1 : fkA1;
    uint32_t gi   = (uint32_t)b * Lsz + lidx;
    uint32_t o0, o1, bits;
#if THREEFRY_PARTITIONABLE
    tf2x32(kk0, kk1, 0u, gi, o0, o1);
    bits = o0 ^ o1;
#else
    {
      uint32_t half = Lsz * (NB / 2);
      if (gi < half) { tf2x32(kk0, kk1, gi, gi + half, o0, o1); bits = o0; }
      else           { tf2x32(kk0, kk1, gi - half, gi, o0, o1); bits = o1; }
    }
#endif
    float eps = __uint_as_float((bits >> 9) | 0x3f800000u) - 1.0f;

    // fast f32 sigmoid; exact f64 only in the ambiguity window. Decisions
    // identical to the pure-f64 path (validated R8-R16, absmax 0.0).
    float pf = 1.0f / (1.0f + __expf(-t2));
    bool gate;
    if (fabsf(pf - eps) > 1e-4f) {
      gate = (pf >= eps);
    } else {
      double ex = exp(-(double)t2);
      float pro = (float)(1.0 / (1.0 + ex));
      gate = (pro >= eps);
    }
    if (valid && gate) yacc += wts[e];
  }

  // ---- phase E: wave-shuffle reduction + fused regularizer atomic ----
  {
#pragma unroll
    for (int m = 32; m > 0; m >>= 1) {
      yacc  += __shfl_down(yacc, m, 64);
      v2acc += __shfl_down(v2acc, m, 64);
    }
    if ((tid & 63) == 0) {
      red8[tid >> 6]       = yacc;
      red8[4 + (tid >> 6)] = v2acc;
    }
    __syncthreads();
    if (tid == 0) {
      out[b] = w0[0] + wsum_s + ((red8[0] + red8[1]) + (red8[2] + red8[3]));
      float v2 = w2sum_s + ((red8[4] + red8[5]) + (red8[6] + red8[7]));
      // device-scope atomic; out[NB] zeroed by sfis_setup each launch.
      // Order nondeterminism perturbs the sum at ~1e-10 rel — << threshold.
      atomicAdd(&out[NB], 1.0e-4f * v2);   // BETA
    }
  }
}

extern "C" void kernel_launch(void* const* d_in, const int* in_sizes, int n_in,
                              void* d_out, int out_size, void* d_ws, size_t ws_size,
                              hipStream_t stream) {
  (void)in_sizes; (void)n_in; (void)out_size; (void)ws_size;
  const int*   x       = (const int*)  d_in[0];
  const float* M       = (const float*)d_in[1];
  const float* w0      = (const float*)d_in[2];
  const float* w_table = (const float*)d_in[3];
  const float* V_table = (const float*)d_in[4];
  const float* Z_table = (const float*)d_in[5];
  const float* W1      = (const float*)d_in[6];
  const float* b1      = (const float*)d_in[7];
  const float* W2      = (const float*)d_in[8];
  const float* b2      = (const float*)d_in[9];
  float* out  = (float*)d_out;

  // d_ws layout: [0,1376) descs | [2048,10240) W1hi | [10240,18432) W1lo
  unsigned short* ws_descs = (unsigned short*)d_ws;
  unsigned short* ws_w1hi  = (unsigned short*)((char*)d_ws + 2048);
  unsigned short* ws_w1lo  = (unsigned short*)((char*)d_ws + 10240);

  hipLaunchKernelGGL(sfis_setup, dim3(17), dim3(256), 0, stream,
                     W1, ws_descs, ws_w1hi, ws_w1lo, out);
  hipLaunchKernelGGL(sfis_main, dim3(NB), dim3(256), 0, stream,
                     x, M, w0, w_table, V_table, Z_table, b1, W2, b2,
                     ws_descs, ws_w1hi, ws_w1lo, out);
}